// Round 1
// baseline (688.759 us; speedup 1.0000x reference)
//
#include <hip/hip_runtime.h>
#include <hip/hip_bf16.h>
#include <math.h>

typedef __bf16 bf16x8 __attribute__((ext_vector_type(8)));
typedef __bf16 bf16x4 __attribute__((ext_vector_type(4)));
typedef float f32x4 __attribute__((ext_vector_type(4)));

#define AS1 __attribute__((address_space(1)))
#define AS3 __attribute__((address_space(3)))

__device__ __forceinline__ void gll16(const __bf16* g, __bf16* l) {
    __builtin_amdgcn_global_load_lds((const AS1 unsigned int*)g,
                                     (AS3 unsigned int*)l, 16, 0, 0);
}

__device__ __forceinline__ unsigned pkbf(float a, float b) {
    union { __bf16 h[2]; unsigned u; } t;
    t.h[0] = (__bf16)a; t.h[1] = (__bf16)b;
    return t.u;
}

// ---------------------------------------------------------------------------
// All 6 weight transposes (fp32 [K,N] -> bf16 [N,K]) in one launch.
// ---------------------------------------------------------------------------
__global__ __launch_bounds__(256) void transpose_all(
    const float* __restrict__ Wq, const float* __restrict__ Wk,
    const float* __restrict__ Wv, const float* __restrict__ Wo,
    const float* __restrict__ W1, const float* __restrict__ W2,
    __bf16* __restrict__ Wqt, __bf16* __restrict__ Wkt,
    __bf16* __restrict__ Wvt, __bf16* __restrict__ Wot,
    __bf16* __restrict__ W1t, __bf16* __restrict__ W2t) {
    int g = blockIdx.x;
    const float* W; __bf16* Wt; int K, N, kt, nt;
    if (g < 4096) {
        int mi = g >> 10, loc = g & 1023;
        K = 1024; N = 1024; kt = loc >> 5; nt = loc & 31;
        W  = mi == 0 ? Wq  : mi == 1 ? Wk  : mi == 2 ? Wv  : Wo;
        Wt = mi == 0 ? Wqt : mi == 1 ? Wkt : mi == 2 ? Wvt : Wot;
    } else if (g < 8192) {
        int loc = g - 4096; W = W1; Wt = W1t;
        K = 1024; N = 4096; kt = loc >> 7; nt = loc & 127;
    } else {
        int loc = g - 8192; W = W2; Wt = W2t;
        K = 4096; N = 1024; kt = loc >> 5; nt = loc & 31;
    }
    int k0 = kt * 32, n0 = nt * 32;
    __shared__ float tile[32][33];
    int tx = threadIdx.x & 31, ty = threadIdx.x >> 5;
    #pragma unroll
    for (int j = ty; j < 32; j += 8)
        tile[j][tx] = W[(size_t)(k0 + j) * N + n0 + tx];
    __syncthreads();
    #pragma unroll
    for (int j = ty; j < 32; j += 8)
        Wt[(size_t)(n0 + j) * K + k0 + tx] = (__bf16)tile[tx][j];
}

// ---------------------------------------------------------------------------
// Fused 3-way pre-norm.
// ---------------------------------------------------------------------------
__global__ __launch_bounds__(256) void ln3_kernel(
    const float* __restrict__ q, const float* __restrict__ k,
    const float* __restrict__ v,
    const float* __restrict__ g1, const float* __restrict__ b1,
    const float* __restrict__ g2, const float* __restrict__ b2,
    float* __restrict__ qln, __bf16* __restrict__ qbf,
    __bf16* __restrict__ kbf, __bf16* __restrict__ vbf) {
    const int E = 1024;
    int which = blockIdx.y;
    const float* x = which == 0 ? q : which == 1 ? k : v;
    const float* g = which == 0 ? g1 : g2;
    const float* bb = which == 0 ? b1 : b2;
    float* o32 = which == 0 ? qln : nullptr;
    __bf16* obf = which == 0 ? qbf : which == 1 ? kbf : vbf;

    size_t row = blockIdx.x;
    int t = threadIdx.x;
    float4 val = ((const float4*)(x + row * E))[t];
    float s  = val.x + val.y + val.z + val.w;
    float s2 = val.x * val.x + val.y * val.y + val.z * val.z + val.w * val.w;
    #pragma unroll
    for (int off = 32; off >= 1; off >>= 1) {
        s  += __shfl_down(s, off);
        s2 += __shfl_down(s2, off);
    }
    __shared__ float red[2][4];
    int wid = t >> 6, lane = t & 63;
    if (lane == 0) { red[0][wid] = s; red[1][wid] = s2; }
    __syncthreads();
    if (t == 0) {
        float S1 = red[0][0] + red[0][1] + red[0][2] + red[0][3];
        float S2 = red[1][0] + red[1][1] + red[1][2] + red[1][3];
        float mean = S1 / E;
        float var  = S2 / E - mean * mean;
        red[0][0] = mean;
        red[1][0] = 1.0f / sqrtf(var + 1e-5f);
    }
    __syncthreads();
    float mean = red[0][0], rstd = red[1][0];
    float4 gv = ((const float4*)g)[t];
    float4 bv = ((const float4*)bb)[t];
    float y0 = (val.x - mean) * rstd * gv.x + bv.x;
    float y1 = (val.y - mean) * rstd * gv.y + bv.y;
    float y2 = (val.z - mean) * rstd * gv.z + bv.z;
    float y3 = (val.w - mean) * rstd * gv.w + bv.w;
    if (o32) ((float4*)(o32 + row * E))[t] = make_float4(y0, y1, y2, y3);
    bf16x4 o;
    o[0] = (__bf16)y0; o[1] = (__bf16)y1; o[2] = (__bf16)y2; o[3] = (__bf16)y3;
    ((bf16x4*)(obf + row * E))[t] = o;
}

// single-input LN (final norm), bf16 out
__global__ __launch_bounds__(256) void ln_kernel(const float* __restrict__ x,
                                                 const float* __restrict__ g,
                                                 const float* __restrict__ bb,
                                                 __bf16* __restrict__ outbf) {
    const int E = 1024;
    size_t row = blockIdx.x;
    int t = threadIdx.x;
    float4 v = ((const float4*)(x + row * E))[t];
    float s  = v.x + v.y + v.z + v.w;
    float s2 = v.x * v.x + v.y * v.y + v.z * v.z + v.w * v.w;
    #pragma unroll
    for (int off = 32; off >= 1; off >>= 1) {
        s  += __shfl_down(s, off);
        s2 += __shfl_down(s2, off);
    }
    __shared__ float red[2][4];
    int wid = t >> 6, lane = t & 63;
    if (lane == 0) { red[0][wid] = s; red[1][wid] = s2; }
    __syncthreads();
    if (t == 0) {
        float S1 = red[0][0] + red[0][1] + red[0][2] + red[0][3];
        float S2 = red[1][0] + red[1][1] + red[1][2] + red[1][3];
        float mean = S1 / E;
        float var  = S2 / E - mean * mean;
        red[0][0] = mean;
        red[1][0] = 1.0f / sqrtf(var + 1e-5f);
    }
    __syncthreads();
    float mean = red[0][0], rstd = red[1][0];
    float4 gv = ((const float4*)g)[t];
    float4 bv = ((const float4*)bb)[t];
    bf16x4 o;
    o[0] = (__bf16)((v.x - mean) * rstd * gv.x + bv.x);
    o[1] = (__bf16)((v.y - mean) * rstd * gv.y + bv.y);
    o[2] = (__bf16)((v.z - mean) * rstd * gv.z + bv.z);
    o[3] = (__bf16)((v.w - mean) * rstd * gv.w + bv.w);
    ((bf16x4*)(outbf + row * E))[t] = o;
}

// ---------------------------------------------------------------------------
// GEMM 128x128 tile, 1D grid with XCD row-affinity swizzle:
//   x8 = id&7 (assumed XCD), col = (id>>3)%GX, row = ((id>>3)/GX)*8 + x8.
// All blocks of one row-panel land on one XCD -> A-panel fetched once/XCD.
// Swapped-operand MFMA (C^T accum layout: lane row=l15, col=quad*4+r).
// Column split at splitN selects (A2,Bt2) for merged QK.
// EPI: 0 bf16*sc out; 1 f32+bias+resid; 2 bf16+bias+gelu.
// ---------------------------------------------------------------------------
template <int EPI>
__global__ __launch_bounds__(256) void gemm128(const __bf16* __restrict__ A,
                                               const __bf16* __restrict__ A2,
                                               const __bf16* __restrict__ Bt,
                                               const __bf16* __restrict__ Bt2,
                                               const float* __restrict__ bias,
                                               const float* __restrict__ resid,
                                               void* __restrict__ Cout,
                                               int M, int N, int K,
                                               int splitN, float scale) {
    __shared__ __bf16 As[128 * 64];
    __shared__ __bf16 Bs[128 * 64];
    int tid  = threadIdx.x;
    int lane = tid & 63, wid = tid >> 6;
    int quad = lane >> 4, l15 = lane & 15;
    int waveM = wid >> 1, waveN = wid & 1;

    int GX = N >> 7;
    int id = blockIdx.x;
    int x8 = id & 7, t = id >> 3;
    size_t rowBase = (size_t)((t / GX) * 8 + x8) * 128;
    size_t colBase = (size_t)(t % GX) * 128;

    const __bf16* Ap = A; const __bf16* Bp = Bt;
    size_t colLoc = colBase;
    float sc = scale;
    if ((int)colBase >= splitN) { Ap = A2; Bp = Bt2; colLoc = colBase - splitN; sc = 1.0f; }

    int lrow8  = lane >> 3;
    int lchunk = (lane & 7) ^ lrow8;
    const __bf16* Ag0 = Ap + (rowBase + wid * 32 + lrow8) * (size_t)K + lchunk * 8;
    const __bf16* Bg0 = Bp + (colLoc  + wid * 32 + lrow8) * (size_t)K + lchunk * 8;
    __bf16* AsB = &As[(wid * 32) * 64];
    __bf16* BsB = &Bs[(wid * 32) * 64];

    f32x4 acc[4][4] = {};
    int swz = l15 & 7;

    for (int kb = 0; kb < K; kb += 64) {
        __syncthreads();
        #pragma unroll
        for (int i = 0; i < 4; i++) {
            gll16(Ag0 + (size_t)i * 8 * K + kb, AsB + i * 512);
            gll16(Bg0 + (size_t)i * 8 * K + kb, BsB + i * 512);
        }
        __syncthreads();
        #pragma unroll
        for (int ks = 0; ks < 2; ks++) {
            int p = ((ks * 4 + quad) ^ swz) * 8;
            bf16x8 af[4], bfr[4];
            #pragma unroll
            for (int mi = 0; mi < 4; mi++)
                af[mi] = *(const bf16x8*)&As[(waveM * 64 + mi * 16 + l15) * 64 + p];
            #pragma unroll
            for (int ni = 0; ni < 4; ni++)
                bfr[ni] = *(const bf16x8*)&Bs[(waveN * 64 + ni * 16 + l15) * 64 + p];
            #pragma unroll
            for (int mi = 0; mi < 4; mi++)
                #pragma unroll
                for (int ni = 0; ni < 4; ni++)
                    acc[mi][ni] = __builtin_amdgcn_mfma_f32_16x16x32_bf16(
                        bfr[ni], af[mi], acc[mi][ni], 0, 0, 0);  // swapped: C^T
        }
    }

    #pragma unroll
    for (int mi = 0; mi < 4; mi++)
    #pragma unroll
    for (int ni = 0; ni < 4; ni++) {
        size_t row = rowBase + waveM * 64 + mi * 16 + l15;
        size_t col = colBase + waveN * 64 + ni * 16 + quad * 4;
        f32x4 v = acc[mi][ni];
        if (EPI == 1) {
            float4 b4 = *(const float4*)&bias[col];
            float4 r4 = *(const float4*)&resid[row * N + col];
            float4 o;
            o.x = v[0] + b4.x + r4.x; o.y = v[1] + b4.y + r4.y;
            o.z = v[2] + b4.z + r4.z; o.w = v[3] + b4.w + r4.w;
            *(float4*)&((float*)Cout)[row * N + col] = o;
        } else if (EPI == 2) {
            float4 b4 = *(const float4*)&bias[col];
            bf16x4 pk;
            #pragma unroll
            for (int r = 0; r < 4; r++) {
                float t2 = v[r] + ((const float*)&b4)[r];
                pk[r] = (__bf16)(0.5f * t2 * (1.0f + erff(t2 * 0.70710678118654752f)));
            }
            *(bf16x4*)&((__bf16*)Cout)[row * N + col] = pk;
        } else {
            bf16x4 pk;
            #pragma unroll
            for (int r = 0; r < 4; r++) pk[r] = (__bf16)(v[r] * sc);
            *(bf16x4*)&((__bf16*)Cout)[row * N + col] = pk;
        }
    }
}

// ---------------------------------------------------------------------------
// V projection GEMM (non-swapped MFMA) writing V^T [E, M], packed stores.
// Same XCD row-affinity swizzle.
// ---------------------------------------------------------------------------
__global__ __launch_bounds__(256) void gemmV(const __bf16* __restrict__ A,
                                             const __bf16* __restrict__ Bt,
                                             __bf16* __restrict__ Cout,
                                             int M, int N, int K) {
    __shared__ __bf16 As[128 * 64];
    __shared__ __bf16 Bs[128 * 64];
    int tid  = threadIdx.x;
    int lane = tid & 63, wid = tid >> 6;
    int quad = lane >> 4, l15 = lane & 15;
    int waveM = wid >> 1, waveN = wid & 1;

    int GX = N >> 7;
    int id = blockIdx.x;
    int x8 = id & 7, t = id >> 3;
    size_t rowBase = (size_t)((t / GX) * 8 + x8) * 128;
    size_t colBase = (size_t)(t % GX) * 128;

    int lrow8  = lane >> 3;
    int lchunk = (lane & 7) ^ lrow8;
    const __bf16* Ag0 = A  + (rowBase + wid * 32 + lrow8) * (size_t)K + lchunk * 8;
    const __bf16* Bg0 = Bt + (colBase + wid * 32 + lrow8) * (size_t)K + lchunk * 8;
    __bf16* AsB = &As[(wid * 32) * 64];
    __bf16* BsB = &Bs[(wid * 32) * 64];

    f32x4 acc[4][4] = {};
    int swz = l15 & 7;

    for (int kb = 0; kb < K; kb += 64) {
        __syncthreads();
        #pragma unroll
        for (int i = 0; i < 4; i++) {
            gll16(Ag0 + (size_t)i * 8 * K + kb, AsB + i * 512);
            gll16(Bg0 + (size_t)i * 8 * K + kb, BsB + i * 512);
        }
        __syncthreads();
        #pragma unroll
        for (int ks = 0; ks < 2; ks++) {
            int p = ((ks * 4 + quad) ^ swz) * 8;
            bf16x8 af[4], bfr[4];
            #pragma unroll
            for (int mi = 0; mi < 4; mi++)
                af[mi] = *(const bf16x8*)&As[(waveM * 64 + mi * 16 + l15) * 64 + p];
            #pragma unroll
            for (int ni = 0; ni < 4; ni++)
                bfr[ni] = *(const bf16x8*)&Bs[(waveN * 64 + ni * 16 + l15) * 64 + p];
            #pragma unroll
            for (int mi = 0; mi < 4; mi++)
                #pragma unroll
                for (int ni = 0; ni < 4; ni++)
                    acc[mi][ni] = __builtin_amdgcn_mfma_f32_16x16x32_bf16(
                        af[mi], bfr[ni], acc[mi][ni], 0, 0, 0);
        }
    }

    #pragma unroll
    for (int mi = 0; mi < 4; mi++)
    #pragma unroll
    for (int ni = 0; ni < 4; ni++) {
        size_t col = colBase + waveN * 64 + ni * 16 + l15;        // dim in E
        size_t m0  = rowBase + waveM * 64 + mi * 16 + quad * 4;   // token
        bf16x4 pk;
        #pragma unroll
        for (int r = 0; r < 4; r++) pk[r] = (__bf16)acc[mi][ni][r];
        *(bf16x4*)&Cout[col * M + m0] = pk;
    }
}

// ---------------------------------------------------------------------------
// Flash attention, transposed-score formulation, 512 threads (8 waves x 16 q).
// ---------------------------------------------------------------------------
__global__ __launch_bounds__(512, 6) void attn_kernel(const __bf16* __restrict__ QK,
                                                      const __bf16* __restrict__ Vt,
                                                      const int* __restrict__ mask,
                                                      __bf16* __restrict__ Out) {
    const int S = 2048, E = 1024, E2 = 2048, M = 8192;
    int qt = blockIdx.x, bh = blockIdx.y;
    int b = bh >> 4, h = bh & 15;
    int q0 = qt * 128;
    int tid = threadIdx.x, lane = tid & 63, wid = tid >> 6;  // wid 0..7
    int quad = lane >> 4, l15 = lane & 15;

    __shared__ __bf16 KV[2][2 * 4096];  // [buf][Ks 64x64 | Vs 64x64]

    bf16x8 aq[2];
    #pragma unroll
    for (int hh = 0; hh < 2; hh++) {
        size_t row = (size_t)(b * S + q0 + wid * 16 + l15);
        aq[hh] = *(const bf16x8*)(QK + row * E2 + h * 64 + hh * 32 + quad * 8);
    }

    int lrow8  = lane >> 3;
    int lchunk = (lane & 7) ^ lrow8;
    const __bf16* Kg0 = QK + (size_t)(b * S + wid * 8 + lrow8) * E2 + 1024 + h * 64 + lchunk * 8;
    const __bf16* Vg0 = Vt + (size_t)(h * 64 + wid * 8 + lrow8) * M + b * S + lchunk * 8;

    int srcA = ((quad & 1) * 2) * 16 + l15;
    int srcB = srcA + 16;
    bool selHi = (quad >= 2);
    int swz = l15 & 7;

    f32x4 accO[4] = {};
    float accl = 0.f;

    gll16(Kg0, &KV[0][wid * 512]);
    gll16(Vg0, &KV[0][4096 + wid * 512]);
    __syncthreads();

    for (int kt = 0; kt < S / 64; kt++) {
        int k0 = kt * 64;
        int buf = kt & 1;
        if (kt + 1 < S / 64) {
            int kn = k0 + 64;
            gll16(Kg0 + (size_t)kn * E2, &KV[buf ^ 1][wid * 512]);
            gll16(Vg0 + kn,              &KV[buf ^ 1][4096 + wid * 512]);
        }
        const __bf16* Ksb = &KV[buf][0];
        const __bf16* Vsb = &KV[buf][4096];

        f32x4 sa[4];
        #pragma unroll
        for (int nt = 0; nt < 4; nt++) {
            bf16x8 a0 = *(const bf16x8*)&Ksb[(nt * 16 + l15) * 64 + ((quad) ^ swz) * 8];
            bf16x8 a1 = *(const bf16x8*)&Ksb[(nt * 16 + l15) * 64 + ((4 + quad) ^ swz) * 8];
            f32x4 a = {};
            a = __builtin_amdgcn_mfma_f32_16x16x32_bf16(a0, aq[0], a, 0, 0, 0);
            a = __builtin_amdgcn_mfma_f32_16x16x32_bf16(a1, aq[1], a, 0, 0, 0);
            sa[nt] = a;
        }

        unsigned pd[4][2];
        #pragma unroll
        for (int nt = 0; nt < 4; nt++) {
            int4 mz = *(const int4*)&mask[b * S + k0 + nt * 16 + quad * 4];
            float p0 = mz.x ? __expf(sa[nt][0]) : 0.f;
            float p1 = mz.y ? __expf(sa[nt][1]) : 0.f;
            float p2 = mz.z ? __expf(sa[nt][2]) : 0.f;
            float p3 = mz.w ? __expf(sa[nt][3]) : 0.f;
            accl += (p0 + p1) + (p2 + p3);
            pd[nt][0] = pkbf(p0, p1);
            pd[nt][1] = pkbf(p2, p3);
        }

        bf16x8 bfrag[2];
        #pragma unroll
        for (int hh = 0; hh < 2; hh++) {
            int ntLo = 2 * hh;
            unsigned dA0 = __shfl((int)pd[ntLo][0], srcA, 64);
            unsigned dB0 = __shfl((int)pd[ntLo + 1][0], srcA, 64);
            unsigned dA1 = __shfl((int)pd[ntLo][1], srcA, 64);
            unsigned dB1 = __shfl((int)pd[ntLo + 1][1], srcA, 64);
            unsigned dA2 = __shfl((int)pd[ntLo][0], srcB, 64);
            unsigned dB2 = __shfl((int)pd[ntLo + 1][0], srcB, 64);
            unsigned dA3 = __shfl((int)pd[ntLo][1], srcB, 64);
            unsigned dB3 = __shfl((int)pd[ntLo + 1][1], srcB, 64);
            union { unsigned u[4]; bf16x8 v; } w;
            w.u[0] = selHi ? dB0 : dA0;
            w.u[1] = selHi ? dB1 : dA1;
            w.u[2] = selHi ? dB2 : dA2;
            w.u[3] = selHi ? dB3 : dA3;
            bfrag[hh] = w.v;
        }

        #pragma unroll
        for (int dt = 0; dt < 4; dt++) {
            bf16x8 v0 = *(const bf16x8*)&Vsb[(dt * 16 + l15) * 64 + ((quad) ^ swz) * 8];
            bf16x8 v1 = *(const bf16x8*)&Vsb[(dt * 16 + l15) * 64 + ((4 + quad) ^ swz) * 8];
            accO[dt] = __builtin_amdgcn_mfma_f32_16x16x32_bf16(v0, bfrag[0], accO[dt], 0, 0, 0);
            accO[dt] = __builtin_amdgcn_mfma_f32_16x16x32_bf16(v1, bfrag[1], accO[dt], 0, 0, 0);
        }
        __syncthreads();
    }

    float l = accl;
    l += __shfl_xor(l, 16, 64);
    l += __shfl_xor(l, 32, 64);
    float inv = 1.0f / l;

    #pragma unroll
    for (int dt = 0; dt < 4; dt++) {
        size_t row = (size_t)(b * S + q0 + wid * 16 + l15);
        bf16x4 pk;
        #pragma unroll
        for (int r = 0; r < 4; r++) pk[r] = (__bf16)(accO[dt][r] * inv);
        *(bf16x4*)&Out[row * E + h * 64 + dt * 16 + quad * 4] = pk;
    }
}

// ---------------------------------------------------------------------------
// Launch
// ---------------------------------------------------------------------------
extern "C" void kernel_launch(void* const* d_in, const int* in_sizes, int n_in,
                              void* d_out, int out_size, void* d_ws, size_t ws_size,
                              hipStream_t stream) {
    const int Bb = 4, S = 2048, E = 1024, FF = 4096;
    const int M = Bb * S;  // 8192

    const float* value = (const float*)d_in[0];
    const float* key   = (const float*)d_in[1];
    const float* query = (const float*)d_in[2];
    const int*   mask  = (const int*)d_in[3];
    const float* Wv    = (const float*)d_in[4];
    const float* Wk    = (const float*)d_in[5];
    const float* Wq    = (const float*)d_in[6];
    const float* Wo    = (const float*)d_in[7];
    const float* bo    = (const float*)d_in[8];
    const float* ln1_g = (const float*)d_in[9];
    const float* ln1_b = (const float*)d_in[10];
    const float* ln2_g = (const float*)d_in[11];
    const float* ln2_b = (const float*)d_in[12];
    const float* lnf_g = (const float*)d_in[13];
    const float* lnf_b = (const float*)d_in[14];
    const float* W1    = (const float*)d_in[15];
    const float* b1    = (const float*)d_in[16];
    const float* W2    = (const float*)d_in[17];
    const float* b2    = (const float*)d_in[18];

    char* ws = (char*)d_ws;
    const size_t MB = 1024 * 1024;
    __bf16* Wqt = (__bf16*)(ws + 0 * MB);
    __bf16* Wkt = (__bf16*)(ws + 2 * MB);
    __bf16* Wvt = (__bf16*)(ws + 4 * MB);
    __bf16* Wot = (__bf16*)(ws + 6 * MB);
    __bf16* W1t = (__bf16*)(ws + 8 * MB);    // [FF, E]
    __bf16* W2t = (__bf16*)(ws + 16 * MB);   // [E, FF]
    __bf16* q_bf = (__bf16*)(ws + 24 * MB);
    __bf16* k_bf = (__bf16*)(ws + 40 * MB);
    __bf16* v_bf = (__bf16*)(ws + 56 * MB);
    __bf16* QKb  = (__bf16*)(ws + 72 * MB);  // [M, 2E]
    __bf16* Vtg  = (__bf16*)(ws + 104 * MB); // V^T [E, M]
    __bf16* attn = q_bf;
    __bf16* x_ln = k_bf;
    __bf16* h1   = v_bf;                     // [M, FF] 64MB
    float*  qln  = (float*)(ws + 120 * MB);
    float*  x32  = (float*)(ws + 152 * MB);

    transpose_all<<<12288, 256, 0, stream>>>(Wq, Wk, Wv, Wo, W1, W2,
                                             Wqt, Wkt, Wvt, Wot, W1t, W2t);

    ln3_kernel<<<dim3(M, 3), 256, 0, stream>>>(query, key, value,
                                               ln1_g, ln1_b, ln2_g, ln2_b,
                                               qln, q_bf, k_bf, v_bf);

    // merged Q|K projection -> QKb [M, 2E]; Q side scaled 1/8. grid 16*64.
    gemm128<0><<<16 * 64, 256, 0, stream>>>(
        q_bf, k_bf, Wqt, Wkt, nullptr, nullptr, QKb, M, 2 * E, E, E, 0.125f);

    // V projection -> V^T [E, M]. grid 8*64.
    gemmV<<<8 * 64, 256, 0, stream>>>(v_bf, Wvt, Vtg, M, E, E);

    attn_kernel<<<dim3(S / 128, Bb * 16), 512, 0, stream>>>(QKb, Vtg, mask, attn);

    // out proj + bias + residual(qln) -> x32 (f32). grid 8*64.
    gemm128<1><<<8 * 64, 256, 0, stream>>>(
        attn, attn, Wot, Wot, bo, qln, x32, M, E, E, E, 1.0f);

    ln_kernel<<<M, 256, 0, stream>>>(x32, lnf_g, lnf_b, x_ln);

    // FFN1: grid 32*64.
    gemm128<2><<<32 * 64, 256, 0, stream>>>(
        x_ln, x_ln, W1t, W1t, b1, nullptr, h1, M, FF, E, FF, 1.0f);
    // FFN2: grid 8*64.
    gemm128<1><<<8 * 64, 256, 0, stream>>>(
        h1, h1, W2t, W2t, b2, x32, (float*)d_out, M, E, FF, E, 1.0f);
}

// Round 2
// 681.836 us; speedup vs baseline: 1.0102x; 1.0102x over previous
//
#include <hip/hip_runtime.h>
#include <hip/hip_bf16.h>
#include <math.h>

typedef __bf16 bf16x8 __attribute__((ext_vector_type(8)));
typedef __bf16 bf16x4 __attribute__((ext_vector_type(4)));
typedef float f32x4 __attribute__((ext_vector_type(4)));
typedef float f32x2 __attribute__((ext_vector_type(2)));
typedef short s16x4 __attribute__((ext_vector_type(4)));

#define AS1 __attribute__((address_space(1)))
#define AS3 __attribute__((address_space(3)))

__device__ __forceinline__ void gll16(const __bf16* g, __bf16* l) {
    __builtin_amdgcn_global_load_lds((const AS1 unsigned int*)g,
                                     (AS3 unsigned int*)l, 16, 0, 0);
}

#if __has_builtin(__builtin_amdgcn_exp2f)
#define EXP2(x) __builtin_amdgcn_exp2f(x)
#else
#define EXP2(x) __expf((x) * 0.69314718055994530942f)
#endif

// PV matmul with K=16 MFMA: B-operand layout (lane holds B[k=quad*4+j][q=l15])
// matches the QK^T score output layout exactly -> no cross-lane shuffle.
__device__ __forceinline__ f32x4 mfma16x16(bf16x4 a, bf16x4 b, f32x4 c) {
#if __has_builtin(__builtin_amdgcn_mfma_f32_16x16x16bf16_1k)
    union { bf16x4 h; s16x4 s; } ua, ub;
    ua.h = a; ub.h = b;
    return __builtin_amdgcn_mfma_f32_16x16x16bf16_1k(ua.s, ub.s, c, 0, 0, 0);
#else
    f32x4 d = c;
    asm volatile("v_mfma_f32_16x16x16_bf16 %0, %1, %2, %0"
                 : "+v"(d) : "v"(a), "v"(b));
    return d;
#endif
}

// ---------------------------------------------------------------------------
// All 6 weight transposes (fp32 [K,N] -> bf16 [N,K]) in one launch.
// ---------------------------------------------------------------------------
__global__ __launch_bounds__(256) void transpose_all(
    const float* __restrict__ Wq, const float* __restrict__ Wk,
    const float* __restrict__ Wv, const float* __restrict__ Wo,
    const float* __restrict__ W1, const float* __restrict__ W2,
    __bf16* __restrict__ Wqt, __bf16* __restrict__ Wkt,
    __bf16* __restrict__ Wvt, __bf16* __restrict__ Wot,
    __bf16* __restrict__ W1t, __bf16* __restrict__ W2t) {
    int g = blockIdx.x;
    const float* W; __bf16* Wt; int K, N, kt, nt;
    if (g < 4096) {
        int mi = g >> 10, loc = g & 1023;
        K = 1024; N = 1024; kt = loc >> 5; nt = loc & 31;
        W  = mi == 0 ? Wq  : mi == 1 ? Wk  : mi == 2 ? Wv  : Wo;
        Wt = mi == 0 ? Wqt : mi == 1 ? Wkt : mi == 2 ? Wvt : Wot;
    } else if (g < 8192) {
        int loc = g - 4096; W = W1; Wt = W1t;
        K = 1024; N = 4096; kt = loc >> 7; nt = loc & 127;
    } else {
        int loc = g - 8192; W = W2; Wt = W2t;
        K = 4096; N = 1024; kt = loc >> 5; nt = loc & 31;
    }
    int k0 = kt * 32, n0 = nt * 32;
    __shared__ float tile[32][33];
    int tx = threadIdx.x & 31, ty = threadIdx.x >> 5;
    #pragma unroll
    for (int j = ty; j < 32; j += 8)
        tile[j][tx] = W[(size_t)(k0 + j) * N + n0 + tx];
    __syncthreads();
    #pragma unroll
    for (int j = ty; j < 32; j += 8)
        Wt[(size_t)(n0 + j) * K + k0 + tx] = (__bf16)tile[tx][j];
}

// ---------------------------------------------------------------------------
// Fused 3-way pre-norm.
// ---------------------------------------------------------------------------
__global__ __launch_bounds__(256) void ln3_kernel(
    const float* __restrict__ q, const float* __restrict__ k,
    const float* __restrict__ v,
    const float* __restrict__ g1, const float* __restrict__ b1,
    const float* __restrict__ g2, const float* __restrict__ b2,
    float* __restrict__ qln, __bf16* __restrict__ qbf,
    __bf16* __restrict__ kbf, __bf16* __restrict__ vbf) {
    const int E = 1024;
    int which = blockIdx.y;
    const float* x = which == 0 ? q : which == 1 ? k : v;
    const float* g = which == 0 ? g1 : g2;
    const float* bb = which == 0 ? b1 : b2;
    float* o32 = which == 0 ? qln : nullptr;
    __bf16* obf = which == 0 ? qbf : which == 1 ? kbf : vbf;

    size_t row = blockIdx.x;
    int t = threadIdx.x;
    float4 val = ((const float4*)(x + row * E))[t];
    float s  = val.x + val.y + val.z + val.w;
    float s2 = val.x * val.x + val.y * val.y + val.z * val.z + val.w * val.w;
    #pragma unroll
    for (int off = 32; off >= 1; off >>= 1) {
        s  += __shfl_down(s, off);
        s2 += __shfl_down(s2, off);
    }
    __shared__ float red[2][4];
    int wid = t >> 6, lane = t & 63;
    if (lane == 0) { red[0][wid] = s; red[1][wid] = s2; }
    __syncthreads();
    if (t == 0) {
        float S1 = red[0][0] + red[0][1] + red[0][2] + red[0][3];
        float S2 = red[1][0] + red[1][1] + red[1][2] + red[1][3];
        float mean = S1 / E;
        float var  = S2 / E - mean * mean;
        red[0][0] = mean;
        red[1][0] = 1.0f / sqrtf(var + 1e-5f);
    }
    __syncthreads();
    float mean = red[0][0], rstd = red[1][0];
    float4 gv = ((const float4*)g)[t];
    float4 bv = ((const float4*)bb)[t];
    float y0 = (val.x - mean) * rstd * gv.x + bv.x;
    float y1 = (val.y - mean) * rstd * gv.y + bv.y;
    float y2 = (val.z - mean) * rstd * gv.z + bv.z;
    float y3 = (val.w - mean) * rstd * gv.w + bv.w;
    if (o32) ((float4*)(o32 + row * E))[t] = make_float4(y0, y1, y2, y3);
    bf16x4 o;
    o[0] = (__bf16)y0; o[1] = (__bf16)y1; o[2] = (__bf16)y2; o[3] = (__bf16)y3;
    ((bf16x4*)(obf + row * E))[t] = o;
}

// single-input LN (final norm), bf16 out
__global__ __launch_bounds__(256) void ln_kernel(const float* __restrict__ x,
                                                 const float* __restrict__ g,
                                                 const float* __restrict__ bb,
                                                 __bf16* __restrict__ outbf) {
    const int E = 1024;
    size_t row = blockIdx.x;
    int t = threadIdx.x;
    float4 v = ((const float4*)(x + row * E))[t];
    float s  = v.x + v.y + v.z + v.w;
    float s2 = v.x * v.x + v.y * v.y + v.z * v.z + v.w * v.w;
    #pragma unroll
    for (int off = 32; off >= 1; off >>= 1) {
        s  += __shfl_down(s, off);
        s2 += __shfl_down(s2, off);
    }
    __shared__ float red[2][4];
    int wid = t >> 6, lane = t & 63;
    if (lane == 0) { red[0][wid] = s; red[1][wid] = s2; }
    __syncthreads();
    if (t == 0) {
        float S1 = red[0][0] + red[0][1] + red[0][2] + red[0][3];
        float S2 = red[1][0] + red[1][1] + red[1][2] + red[1][3];
        float mean = S1 / E;
        float var  = S2 / E - mean * mean;
        red[0][0] = mean;
        red[1][0] = 1.0f / sqrtf(var + 1e-5f);
    }
    __syncthreads();
    float mean = red[0][0], rstd = red[1][0];
    float4 gv = ((const float4*)g)[t];
    float4 bv = ((const float4*)bb)[t];
    bf16x4 o;
    o[0] = (__bf16)((v.x - mean) * rstd * gv.x + bv.x);
    o[1] = (__bf16)((v.y - mean) * rstd * gv.y + bv.y);
    o[2] = (__bf16)((v.z - mean) * rstd * gv.z + bv.z);
    o[3] = (__bf16)((v.w - mean) * rstd * gv.w + bv.w);
    ((bf16x4*)(outbf + row * E))[t] = o;
}

// ---------------------------------------------------------------------------
// GEMM 128x128 tile, 1D grid with XCD row-affinity swizzle.
// Swapped-operand MFMA (C^T accum layout: lane row=l15, col=quad*4+r).
// Column split at splitN selects (A2,Bt2) for merged QK.
// EPI: 0 bf16*sc out; 1 f32+bias+resid; 2 bf16+bias+gelu.
// ---------------------------------------------------------------------------
template <int EPI>
__global__ __launch_bounds__(256) void gemm128(const __bf16* __restrict__ A,
                                               const __bf16* __restrict__ A2,
                                               const __bf16* __restrict__ Bt,
                                               const __bf16* __restrict__ Bt2,
                                               const float* __restrict__ bias,
                                               const float* __restrict__ resid,
                                               void* __restrict__ Cout,
                                               int M, int N, int K,
                                               int splitN, float scale) {
    __shared__ __bf16 As[128 * 64];
    __shared__ __bf16 Bs[128 * 64];
    int tid  = threadIdx.x;
    int lane = tid & 63, wid = tid >> 6;
    int quad = lane >> 4, l15 = lane & 15;
    int waveM = wid >> 1, waveN = wid & 1;

    int GX = N >> 7;
    int id = blockIdx.x;
    int x8 = id & 7, t = id >> 3;
    size_t rowBase = (size_t)((t / GX) * 8 + x8) * 128;
    size_t colBase = (size_t)(t % GX) * 128;

    const __bf16* Ap = A; const __bf16* Bp = Bt;
    size_t colLoc = colBase;
    float sc = scale;
    if ((int)colBase >= splitN) { Ap = A2; Bp = Bt2; colLoc = colBase - splitN; sc = 1.0f; }

    int lrow8  = lane >> 3;
    int lchunk = (lane & 7) ^ lrow8;
    const __bf16* Ag0 = Ap + (rowBase + wid * 32 + lrow8) * (size_t)K + lchunk * 8;
    const __bf16* Bg0 = Bp + (colLoc  + wid * 32 + lrow8) * (size_t)K + lchunk * 8;
    __bf16* AsB = &As[(wid * 32) * 64];
    __bf16* BsB = &Bs[(wid * 32) * 64];

    f32x4 acc[4][4] = {};
    int swz = l15 & 7;

    for (int kb = 0; kb < K; kb += 64) {
        __syncthreads();
        #pragma unroll
        for (int i = 0; i < 4; i++) {
            gll16(Ag0 + (size_t)i * 8 * K + kb, AsB + i * 512);
            gll16(Bg0 + (size_t)i * 8 * K + kb, BsB + i * 512);
        }
        __syncthreads();
        #pragma unroll
        for (int ks = 0; ks < 2; ks++) {
            int p = ((ks * 4 + quad) ^ swz) * 8;
            bf16x8 af[4], bfr[4];
            #pragma unroll
            for (int mi = 0; mi < 4; mi++)
                af[mi] = *(const bf16x8*)&As[(waveM * 64 + mi * 16 + l15) * 64 + p];
            #pragma unroll
            for (int ni = 0; ni < 4; ni++)
                bfr[ni] = *(const bf16x8*)&Bs[(waveN * 64 + ni * 16 + l15) * 64 + p];
            #pragma unroll
            for (int mi = 0; mi < 4; mi++)
                #pragma unroll
                for (int ni = 0; ni < 4; ni++)
                    acc[mi][ni] = __builtin_amdgcn_mfma_f32_16x16x32_bf16(
                        bfr[ni], af[mi], acc[mi][ni], 0, 0, 0);  // swapped: C^T
        }
    }

    #pragma unroll
    for (int mi = 0; mi < 4; mi++)
    #pragma unroll
    for (int ni = 0; ni < 4; ni++) {
        size_t row = rowBase + waveM * 64 + mi * 16 + l15;
        size_t col = colBase + waveN * 64 + ni * 16 + quad * 4;
        f32x4 v = acc[mi][ni];
        if (EPI == 1) {
            float4 b4 = *(const float4*)&bias[col];
            float4 r4 = *(const float4*)&resid[row * N + col];
            float4 o;
            o.x = v[0] + b4.x + r4.x; o.y = v[1] + b4.y + r4.y;
            o.z = v[2] + b4.z + r4.z; o.w = v[3] + b4.w + r4.w;
            *(float4*)&((float*)Cout)[row * N + col] = o;
        } else if (EPI == 2) {
            float4 b4 = *(const float4*)&bias[col];
            bf16x4 pk;
            #pragma unroll
            for (int r = 0; r < 4; r++) {
                float t2 = v[r] + ((const float*)&b4)[r];
                pk[r] = (__bf16)(0.5f * t2 * (1.0f + erff(t2 * 0.70710678118654752f)));
            }
            *(bf16x4*)&((__bf16*)Cout)[row * N + col] = pk;
        } else {
            bf16x4 pk;
            #pragma unroll
            for (int r = 0; r < 4; r++) pk[r] = (__bf16)(v[r] * sc);
            *(bf16x4*)&((__bf16*)Cout)[row * N + col] = pk;
        }
    }
}

// ---------------------------------------------------------------------------
// V projection GEMM (non-swapped MFMA) writing V^T [E, M], packed stores.
// ---------------------------------------------------------------------------
__global__ __launch_bounds__(256) void gemmV(const __bf16* __restrict__ A,
                                             const __bf16* __restrict__ Bt,
                                             __bf16* __restrict__ Cout,
                                             int M, int N, int K) {
    __shared__ __bf16 As[128 * 64];
    __shared__ __bf16 Bs[128 * 64];
    int tid  = threadIdx.x;
    int lane = tid & 63, wid = tid >> 6;
    int quad = lane >> 4, l15 = lane & 15;
    int waveM = wid >> 1, waveN = wid & 1;

    int GX = N >> 7;
    int id = blockIdx.x;
    int x8 = id & 7, t = id >> 3;
    size_t rowBase = (size_t)((t / GX) * 8 + x8) * 128;
    size_t colBase = (size_t)(t % GX) * 128;

    int lrow8  = lane >> 3;
    int lchunk = (lane & 7) ^ lrow8;
    const __bf16* Ag0 = A  + (rowBase + wid * 32 + lrow8) * (size_t)K + lchunk * 8;
    const __bf16* Bg0 = Bt + (colBase + wid * 32 + lrow8) * (size_t)K + lchunk * 8;
    __bf16* AsB = &As[(wid * 32) * 64];
    __bf16* BsB = &Bs[(wid * 32) * 64];

    f32x4 acc[4][4] = {};
    int swz = l15 & 7;

    for (int kb = 0; kb < K; kb += 64) {
        __syncthreads();
        #pragma unroll
        for (int i = 0; i < 4; i++) {
            gll16(Ag0 + (size_t)i * 8 * K + kb, AsB + i * 512);
            gll16(Bg0 + (size_t)i * 8 * K + kb, BsB + i * 512);
        }
        __syncthreads();
        #pragma unroll
        for (int ks = 0; ks < 2; ks++) {
            int p = ((ks * 4 + quad) ^ swz) * 8;
            bf16x8 af[4], bfr[4];
            #pragma unroll
            for (int mi = 0; mi < 4; mi++)
                af[mi] = *(const bf16x8*)&As[(waveM * 64 + mi * 16 + l15) * 64 + p];
            #pragma unroll
            for (int ni = 0; ni < 4; ni++)
                bfr[ni] = *(const bf16x8*)&Bs[(waveN * 64 + ni * 16 + l15) * 64 + p];
            #pragma unroll
            for (int mi = 0; mi < 4; mi++)
                #pragma unroll
                for (int ni = 0; ni < 4; ni++)
                    acc[mi][ni] = __builtin_amdgcn_mfma_f32_16x16x32_bf16(
                        af[mi], bfr[ni], acc[mi][ni], 0, 0, 0);
        }
    }

    #pragma unroll
    for (int mi = 0; mi < 4; mi++)
    #pragma unroll
    for (int ni = 0; ni < 4; ni++) {
        size_t col = colBase + waveN * 64 + ni * 16 + l15;        // dim in E
        size_t m0  = rowBase + waveM * 64 + mi * 16 + quad * 4;   // token
        bf16x4 pk;
        #pragma unroll
        for (int r = 0; r < 4; r++) pk[r] = (__bf16)acc[mi][ni][r];
        *(bf16x4*)&Cout[col * M + m0] = pk;
    }
}

// ---------------------------------------------------------------------------
// Flash attention, transposed-score formulation, 512 threads (8 waves x 16 q).
// Q side of QKb is pre-scaled by (1/8)*log2(e) so softmax uses raw exp2.
// PV uses 16x16x16 MFMA: B-operand layout == score layout -> zero shuffles.
// ---------------------------------------------------------------------------
__global__ __launch_bounds__(512, 6) void attn_kernel(const __bf16* __restrict__ QK,
                                                      const __bf16* __restrict__ Vt,
                                                      const int* __restrict__ mask,
                                                      __bf16* __restrict__ Out) {
    const int S = 2048, E = 1024, E2 = 2048, M = 8192;
    int qt = blockIdx.x, bh = blockIdx.y;
    int b = bh >> 4, h = bh & 15;
    int q0 = qt * 128;
    int tid = threadIdx.x, lane = tid & 63, wid = tid >> 6;  // wid 0..7
    int quad = lane >> 4, l15 = lane & 15;

    __shared__ __bf16 KV[2][2 * 4096];  // [buf][Ks 64x64 | Vs 64x64]

    bf16x8 aq[2];
    #pragma unroll
    for (int hh = 0; hh < 2; hh++) {
        size_t row = (size_t)(b * S + q0 + wid * 16 + l15);
        aq[hh] = *(const bf16x8*)(QK + row * E2 + h * 64 + hh * 32 + quad * 8);
    }

    int lrow8  = lane >> 3;
    int lchunk = (lane & 7) ^ lrow8;
    const __bf16* Kg0 = QK + (size_t)(b * S + wid * 8 + lrow8) * E2 + 1024 + h * 64 + lchunk * 8;
    const __bf16* Vg0 = Vt + (size_t)(h * 64 + wid * 8 + lrow8) * M + b * S + lchunk * 8;

    int swz = l15 & 7;
    int qh = quad >> 1, ql = quad & 1;

    f32x4 accO[4] = {};
    f32x2 acc2 = {0.f, 0.f};

    gll16(Kg0, &KV[0][wid * 512]);
    gll16(Vg0, &KV[0][4096 + wid * 512]);
    __syncthreads();

    for (int kt = 0; kt < S / 64; kt++) {
        int k0 = kt * 64;
        int buf = kt & 1;
        if (kt + 1 < S / 64) {
            int kn = k0 + 64;
            gll16(Kg0 + (size_t)kn * E2, &KV[buf ^ 1][wid * 512]);
            gll16(Vg0 + kn,              &KV[buf ^ 1][4096 + wid * 512]);
        }
        const __bf16* Ksb = &KV[buf][0];
        const __bf16* Vsb = &KV[buf][4096];

        f32x4 sa[4];
        #pragma unroll
        for (int nt = 0; nt < 4; nt++) {
            bf16x8 a0 = *(const bf16x8*)&Ksb[(nt * 16 + l15) * 64 + ((quad) ^ swz) * 8];
            bf16x8 a1 = *(const bf16x8*)&Ksb[(nt * 16 + l15) * 64 + ((4 + quad) ^ swz) * 8];
            f32x4 a = {};
            a = __builtin_amdgcn_mfma_f32_16x16x32_bf16(a0, aq[0], a, 0, 0, 0);
            a = __builtin_amdgcn_mfma_f32_16x16x32_bf16(a1, aq[1], a, 0, 0, 0);
            sa[nt] = a;
        }

        bf16x4 pb[4];
        #pragma unroll
        for (int nt = 0; nt < 4; nt++) {
            int4 mz = *(const int4*)&mask[b * S + k0 + nt * 16 + quad * 4];
            float p0 = mz.x ? EXP2(sa[nt][0]) : 0.f;
            float p1 = mz.y ? EXP2(sa[nt][1]) : 0.f;
            float p2 = mz.z ? EXP2(sa[nt][2]) : 0.f;
            float p3 = mz.w ? EXP2(sa[nt][3]) : 0.f;
            f32x2 t01; t01[0] = p0; t01[1] = p1;
            f32x2 t23; t23[0] = p2; t23[1] = p3;
            acc2 += t01 + t23;
            bf16x4 pk;
            pk[0] = (__bf16)p0; pk[1] = (__bf16)p1;
            pk[2] = (__bf16)p2; pk[3] = (__bf16)p3;
            pb[nt] = pk;
        }

        // PV: accO[dt] += V^T[d][k] * P^T[k][q] via 16x16x16 MFMA.
        // LDS read swizzle matches gll16 store swizzle (c16 ^ (row&7)).
        #pragma unroll
        for (int dt = 0; dt < 4; dt++) {
            const __bf16* vrow = &Vsb[(dt * 16 + l15) * 64];
            #pragma unroll
            for (int nt = 0; nt < 4; nt++) {
                int c16 = ((nt << 1) + qh) ^ swz;
                bf16x4 va = *(const bf16x4*)&vrow[c16 * 8 + ql * 4];
                accO[dt] = mfma16x16(va, pb[nt], accO[dt]);
            }
        }
        __syncthreads();
    }

    float l = acc2[0] + acc2[1];
    l += __shfl_xor(l, 16, 64);
    l += __shfl_xor(l, 32, 64);
    float inv = 1.0f / l;

    #pragma unroll
    for (int dt = 0; dt < 4; dt++) {
        size_t row = (size_t)(b * S + q0 + wid * 16 + l15);
        bf16x4 pk;
        #pragma unroll
        for (int r = 0; r < 4; r++) pk[r] = (__bf16)(accO[dt][r] * inv);
        *(bf16x4*)&Out[row * E + h * 64 + dt * 16 + quad * 4] = pk;
    }
}

// ---------------------------------------------------------------------------
// Launch
// ---------------------------------------------------------------------------
extern "C" void kernel_launch(void* const* d_in, const int* in_sizes, int n_in,
                              void* d_out, int out_size, void* d_ws, size_t ws_size,
                              hipStream_t stream) {
    const int Bb = 4, S = 2048, E = 1024, FF = 4096;
    const int M = Bb * S;  // 8192

    const float* value = (const float*)d_in[0];
    const float* key   = (const float*)d_in[1];
    const float* query = (const float*)d_in[2];
    const int*   mask  = (const int*)d_in[3];
    const float* Wv    = (const float*)d_in[4];
    const float* Wk    = (const float*)d_in[5];
    const float* Wq    = (const float*)d_in[6];
    const float* Wo    = (const float*)d_in[7];
    const float* bo    = (const float*)d_in[8];
    const float* ln1_g = (const float*)d_in[9];
    const float* ln1_b = (const float*)d_in[10];
    const float* ln2_g = (const float*)d_in[11];
    const float* ln2_b = (const float*)d_in[12];
    const float* lnf_g = (const float*)d_in[13];
    const float* lnf_b = (const float*)d_in[14];
    const float* W1    = (const float*)d_in[15];
    const float* b1    = (const float*)d_in[16];
    const float* W2    = (const float*)d_in[17];
    const float* b2    = (const float*)d_in[18];

    char* ws = (char*)d_ws;
    const size_t MB = 1024 * 1024;
    __bf16* Wqt = (__bf16*)(ws + 0 * MB);
    __bf16* Wkt = (__bf16*)(ws + 2 * MB);
    __bf16* Wvt = (__bf16*)(ws + 4 * MB);
    __bf16* Wot = (__bf16*)(ws + 6 * MB);
    __bf16* W1t = (__bf16*)(ws + 8 * MB);    // [FF, E]
    __bf16* W2t = (__bf16*)(ws + 16 * MB);   // [E, FF]
    __bf16* q_bf = (__bf16*)(ws + 24 * MB);
    __bf16* k_bf = (__bf16*)(ws + 40 * MB);
    __bf16* v_bf = (__bf16*)(ws + 56 * MB);
    __bf16* QKb  = (__bf16*)(ws + 72 * MB);  // [M, 2E]
    __bf16* Vtg  = (__bf16*)(ws + 104 * MB); // V^T [E, M]
    __bf16* attn = q_bf;
    __bf16* x_ln = k_bf;
    __bf16* h1   = v_bf;                     // [M, FF] 64MB
    float*  qln  = (float*)(ws + 120 * MB);
    float*  x32  = (float*)(ws + 152 * MB);

    transpose_all<<<12288, 256, 0, stream>>>(Wq, Wk, Wv, Wo, W1, W2,
                                             Wqt, Wkt, Wvt, Wot, W1t, W2t);

    ln3_kernel<<<dim3(M, 3), 256, 0, stream>>>(query, key, value,
                                               ln1_g, ln1_b, ln2_g, ln2_b,
                                               qln, q_bf, k_bf, v_bf);

    // merged Q|K projection -> QKb [M, 2E]; Q side scaled (1/8)*log2(e).
    gemm128<0><<<16 * 64, 256, 0, stream>>>(
        q_bf, k_bf, Wqt, Wkt, nullptr, nullptr, QKb, M, 2 * E, E, E,
        0.125f * 1.44269504088896f);

    // V projection -> V^T [E, M]. grid 8*64.
    gemmV<<<8 * 64, 256, 0, stream>>>(v_bf, Wvt, Vtg, M, E, E);

    attn_kernel<<<dim3(S / 128, Bb * 16), 512, 0, stream>>>(QKb, Vtg, mask, attn);

    // out proj + bias + residual(qln) -> x32 (f32). grid 8*64.
    gemm128<1><<<8 * 64, 256, 0, stream>>>(
        attn, attn, Wot, Wot, bo, qln, x32, M, E, E, E, 1.0f);

    ln_kernel<<<M, 256, 0, stream>>>(x32, lnf_g, lnf_b, x_ln);

    // FFN1: grid 32*64.
    gemm128<2><<<32 * 64, 256, 0, stream>>>(
        x_ln, x_ln, W1t, W1t, b1, nullptr, h1, M, FF, E, FF, 1.0f);
    // FFN2: grid 8*64.
    gemm128<1><<<8 * 64, 256, 0, stream>>>(
        h1, h1, W2t, W2t, b2, x32, (float*)d_out, M, E, FF, E, 1.0f);
}

// Round 3
// 669.176 us; speedup vs baseline: 1.0293x; 1.0189x over previous
//
#include <hip/hip_runtime.h>
#include <hip/hip_bf16.h>
#include <math.h>

typedef __bf16 bf16x8 __attribute__((ext_vector_type(8)));
typedef __bf16 bf16x4 __attribute__((ext_vector_type(4)));
typedef float f32x4 __attribute__((ext_vector_type(4)));
typedef float f32x2 __attribute__((ext_vector_type(2)));
typedef short s16x4 __attribute__((ext_vector_type(4)));

#define AS1 __attribute__((address_space(1)))
#define AS3 __attribute__((address_space(3)))

__device__ __forceinline__ void gll16(const __bf16* g, __bf16* l) {
    __builtin_amdgcn_global_load_lds((const AS1 unsigned int*)g,
                                     (AS3 unsigned int*)l, 16, 0, 0);
}

#if __has_builtin(__builtin_amdgcn_exp2f)
#define EXP2(x) __builtin_amdgcn_exp2f(x)
#else
#define EXP2(x) __expf((x) * 0.69314718055994530942f)
#endif

// PV matmul with K=16 MFMA: B-operand layout (lane holds B[k=quad*4+j][q=l15])
// matches the QK^T score output layout exactly -> no cross-lane shuffle.
__device__ __forceinline__ f32x4 mfma16x16(bf16x4 a, bf16x4 b, f32x4 c) {
#if __has_builtin(__builtin_amdgcn_mfma_f32_16x16x16bf16_1k)
    union { bf16x4 h; s16x4 s; } ua, ub;
    ua.h = a; ub.h = b;
    return __builtin_amdgcn_mfma_f32_16x16x16bf16_1k(ua.s, ub.s, c, 0, 0, 0);
#else
    f32x4 d = c;
    asm volatile("v_mfma_f32_16x16x16_bf16 %0, %1, %2, %0"
                 : "+v"(d) : "v"(a), "v"(b));
    return d;
#endif
}

// ---------------------------------------------------------------------------
// All 6 weight transposes (fp32 [K,N] -> bf16 [N,K]) in one launch.
// ---------------------------------------------------------------------------
__global__ __launch_bounds__(256) void transpose_all(
    const float* __restrict__ Wq, const float* __restrict__ Wk,
    const float* __restrict__ Wv, const float* __restrict__ Wo,
    const float* __restrict__ W1, const float* __restrict__ W2,
    __bf16* __restrict__ Wqt, __bf16* __restrict__ Wkt,
    __bf16* __restrict__ Wvt, __bf16* __restrict__ Wot,
    __bf16* __restrict__ W1t, __bf16* __restrict__ W2t) {
    int g = blockIdx.x;
    const float* W; __bf16* Wt; int K, N, kt, nt;
    if (g < 4096) {
        int mi = g >> 10, loc = g & 1023;
        K = 1024; N = 1024; kt = loc >> 5; nt = loc & 31;
        W  = mi == 0 ? Wq  : mi == 1 ? Wk  : mi == 2 ? Wv  : Wo;
        Wt = mi == 0 ? Wqt : mi == 1 ? Wkt : mi == 2 ? Wvt : Wot;
    } else if (g < 8192) {
        int loc = g - 4096; W = W1; Wt = W1t;
        K = 1024; N = 4096; kt = loc >> 7; nt = loc & 127;
    } else {
        int loc = g - 8192; W = W2; Wt = W2t;
        K = 4096; N = 1024; kt = loc >> 5; nt = loc & 31;
    }
    int k0 = kt * 32, n0 = nt * 32;
    __shared__ float tile[32][33];
    int tx = threadIdx.x & 31, ty = threadIdx.x >> 5;
    #pragma unroll
    for (int j = ty; j < 32; j += 8)
        tile[j][tx] = W[(size_t)(k0 + j) * N + n0 + tx];
    __syncthreads();
    #pragma unroll
    for (int j = ty; j < 32; j += 8)
        Wt[(size_t)(n0 + j) * K + k0 + tx] = (__bf16)tile[tx][j];
}

// ---------------------------------------------------------------------------
// Fused 3-way pre-norm.
// ---------------------------------------------------------------------------
__global__ __launch_bounds__(256) void ln3_kernel(
    const float* __restrict__ q, const float* __restrict__ k,
    const float* __restrict__ v,
    const float* __restrict__ g1, const float* __restrict__ b1,
    const float* __restrict__ g2, const float* __restrict__ b2,
    float* __restrict__ qln, __bf16* __restrict__ qbf,
    __bf16* __restrict__ kbf, __bf16* __restrict__ vbf) {
    const int E = 1024;
    int which = blockIdx.y;
    const float* x = which == 0 ? q : which == 1 ? k : v;
    const float* g = which == 0 ? g1 : g2;
    const float* bb = which == 0 ? b1 : b2;
    float* o32 = which == 0 ? qln : nullptr;
    __bf16* obf = which == 0 ? qbf : which == 1 ? kbf : vbf;

    size_t row = blockIdx.x;
    int t = threadIdx.x;
    float4 val = ((const float4*)(x + row * E))[t];
    float s  = val.x + val.y + val.z + val.w;
    float s2 = val.x * val.x + val.y * val.y + val.z * val.z + val.w * val.w;
    #pragma unroll
    for (int off = 32; off >= 1; off >>= 1) {
        s  += __shfl_down(s, off);
        s2 += __shfl_down(s2, off);
    }
    __shared__ float red[2][4];
    int wid = t >> 6, lane = t & 63;
    if (lane == 0) { red[0][wid] = s; red[1][wid] = s2; }
    __syncthreads();
    if (t == 0) {
        float S1 = red[0][0] + red[0][1] + red[0][2] + red[0][3];
        float S2 = red[1][0] + red[1][1] + red[1][2] + red[1][3];
        float mean = S1 / E;
        float var  = S2 / E - mean * mean;
        red[0][0] = mean;
        red[1][0] = 1.0f / sqrtf(var + 1e-5f);
    }
    __syncthreads();
    float mean = red[0][0], rstd = red[1][0];
    float4 gv = ((const float4*)g)[t];
    float4 bv = ((const float4*)bb)[t];
    float y0 = (val.x - mean) * rstd * gv.x + bv.x;
    float y1 = (val.y - mean) * rstd * gv.y + bv.y;
    float y2 = (val.z - mean) * rstd * gv.z + bv.z;
    float y3 = (val.w - mean) * rstd * gv.w + bv.w;
    if (o32) ((float4*)(o32 + row * E))[t] = make_float4(y0, y1, y2, y3);
    bf16x4 o;
    o[0] = (__bf16)y0; o[1] = (__bf16)y1; o[2] = (__bf16)y2; o[3] = (__bf16)y3;
    ((bf16x4*)(obf + row * E))[t] = o;
}

// single-input LN (final norm), bf16 out
__global__ __launch_bounds__(256) void ln_kernel(const float* __restrict__ x,
                                                 const float* __restrict__ g,
                                                 const float* __restrict__ bb,
                                                 __bf16* __restrict__ outbf) {
    const int E = 1024;
    size_t row = blockIdx.x;
    int t = threadIdx.x;
    float4 v = ((const float4*)(x + row * E))[t];
    float s  = v.x + v.y + v.z + v.w;
    float s2 = v.x * v.x + v.y * v.y + v.z * v.z + v.w * v.w;
    #pragma unroll
    for (int off = 32; off >= 1; off >>= 1) {
        s  += __shfl_down(s, off);
        s2 += __shfl_down(s2, off);
    }
    __shared__ float red[2][4];
    int wid = t >> 6, lane = t & 63;
    if (lane == 0) { red[0][wid] = s; red[1][wid] = s2; }
    __syncthreads();
    if (t == 0) {
        float S1 = red[0][0] + red[0][1] + red[0][2] + red[0][3];
        float S2 = red[1][0] + red[1][1] + red[1][2] + red[1][3];
        float mean = S1 / E;
        float var  = S2 / E - mean * mean;
        red[0][0] = mean;
        red[1][0] = 1.0f / sqrtf(var + 1e-5f);
    }
    __syncthreads();
    float mean = red[0][0], rstd = red[1][0];
    float4 gv = ((const float4*)g)[t];
    float4 bv = ((const float4*)bb)[t];
    bf16x4 o;
    o[0] = (__bf16)((v.x - mean) * rstd * gv.x + bv.x);
    o[1] = (__bf16)((v.y - mean) * rstd * gv.y + bv.y);
    o[2] = (__bf16)((v.z - mean) * rstd * gv.z + bv.z);
    o[3] = (__bf16)((v.w - mean) * rstd * gv.w + bv.w);
    ((bf16x4*)(outbf + row * E))[t] = o;
}

// ---------------------------------------------------------------------------
// GEMM 128x128 tile, 1D grid with XCD row-affinity swizzle.
// Swapped-operand MFMA (C^T accum layout: lane row=l15, col=quad*4+r).
// Column split at splitN selects (A2,Bt2) for merged QK.
// EPI: 0 bf16*sc out; 1 f32+bias+resid; 2 bf16+bias+gelu.
// ---------------------------------------------------------------------------
template <int EPI>
__global__ __launch_bounds__(256) void gemm128(const __bf16* __restrict__ A,
                                               const __bf16* __restrict__ A2,
                                               const __bf16* __restrict__ Bt,
                                               const __bf16* __restrict__ Bt2,
                                               const float* __restrict__ bias,
                                               const float* __restrict__ resid,
                                               void* __restrict__ Cout,
                                               int M, int N, int K,
                                               int splitN, float scale) {
    __shared__ __bf16 As[128 * 64];
    __shared__ __bf16 Bs[128 * 64];
    int tid  = threadIdx.x;
    int lane = tid & 63, wid = tid >> 6;
    int quad = lane >> 4, l15 = lane & 15;
    int waveM = wid >> 1, waveN = wid & 1;

    int GX = N >> 7;
    int id = blockIdx.x;
    int x8 = id & 7, t = id >> 3;
    size_t rowBase = (size_t)((t / GX) * 8 + x8) * 128;
    size_t colBase = (size_t)(t % GX) * 128;

    const __bf16* Ap = A; const __bf16* Bp = Bt;
    size_t colLoc = colBase;
    float sc = scale;
    if ((int)colBase >= splitN) { Ap = A2; Bp = Bt2; colLoc = colBase - splitN; sc = 1.0f; }

    int lrow8  = lane >> 3;
    int lchunk = (lane & 7) ^ lrow8;
    const __bf16* Ag0 = Ap + (rowBase + wid * 32 + lrow8) * (size_t)K + lchunk * 8;
    const __bf16* Bg0 = Bp + (colLoc  + wid * 32 + lrow8) * (size_t)K + lchunk * 8;
    __bf16* AsB = &As[(wid * 32) * 64];
    __bf16* BsB = &Bs[(wid * 32) * 64];

    f32x4 acc[4][4] = {};
    int swz = l15 & 7;

    for (int kb = 0; kb < K; kb += 64) {
        __syncthreads();
        #pragma unroll
        for (int i = 0; i < 4; i++) {
            gll16(Ag0 + (size_t)i * 8 * K + kb, AsB + i * 512);
            gll16(Bg0 + (size_t)i * 8 * K + kb, BsB + i * 512);
        }
        __syncthreads();
        #pragma unroll
        for (int ks = 0; ks < 2; ks++) {
            int p = ((ks * 4 + quad) ^ swz) * 8;
            bf16x8 af[4], bfr[4];
            #pragma unroll
            for (int mi = 0; mi < 4; mi++)
                af[mi] = *(const bf16x8*)&As[(waveM * 64 + mi * 16 + l15) * 64 + p];
            #pragma unroll
            for (int ni = 0; ni < 4; ni++)
                bfr[ni] = *(const bf16x8*)&Bs[(waveN * 64 + ni * 16 + l15) * 64 + p];
            #pragma unroll
            for (int mi = 0; mi < 4; mi++)
                #pragma unroll
                for (int ni = 0; ni < 4; ni++)
                    acc[mi][ni] = __builtin_amdgcn_mfma_f32_16x16x32_bf16(
                        bfr[ni], af[mi], acc[mi][ni], 0, 0, 0);  // swapped: C^T
        }
    }

    #pragma unroll
    for (int mi = 0; mi < 4; mi++)
    #pragma unroll
    for (int ni = 0; ni < 4; ni++) {
        size_t row = rowBase + waveM * 64 + mi * 16 + l15;
        size_t col = colBase + waveN * 64 + ni * 16 + quad * 4;
        f32x4 v = acc[mi][ni];
        if (EPI == 1) {
            float4 b4 = *(const float4*)&bias[col];
            float4 r4 = *(const float4*)&resid[row * N + col];
            float4 o;
            o.x = v[0] + b4.x + r4.x; o.y = v[1] + b4.y + r4.y;
            o.z = v[2] + b4.z + r4.z; o.w = v[3] + b4.w + r4.w;
            *(float4*)&((float*)Cout)[row * N + col] = o;
        } else if (EPI == 2) {
            float4 b4 = *(const float4*)&bias[col];
            bf16x4 pk;
            #pragma unroll
            for (int r = 0; r < 4; r++) {
                float t2 = v[r] + ((const float*)&b4)[r];
                pk[r] = (__bf16)(0.5f * t2 * (1.0f + erff(t2 * 0.70710678118654752f)));
            }
            *(bf16x4*)&((__bf16*)Cout)[row * N + col] = pk;
        } else {
            bf16x4 pk;
            #pragma unroll
            for (int r = 0; r < 4; r++) pk[r] = (__bf16)(v[r] * sc);
            *(bf16x4*)&((__bf16*)Cout)[row * N + col] = pk;
        }
    }
}

// ---------------------------------------------------------------------------
// V projection GEMM (non-swapped MFMA) writing V^T [E, M], packed stores.
// ---------------------------------------------------------------------------
__global__ __launch_bounds__(256) void gemmV(const __bf16* __restrict__ A,
                                             const __bf16* __restrict__ Bt,
                                             __bf16* __restrict__ Cout,
                                             int M, int N, int K) {
    __shared__ __bf16 As[128 * 64];
    __shared__ __bf16 Bs[128 * 64];
    int tid  = threadIdx.x;
    int lane = tid & 63, wid = tid >> 6;
    int quad = lane >> 4, l15 = lane & 15;
    int waveM = wid >> 1, waveN = wid & 1;

    int GX = N >> 7;
    int id = blockIdx.x;
    int x8 = id & 7, t = id >> 3;
    size_t rowBase = (size_t)((t / GX) * 8 + x8) * 128;
    size_t colBase = (size_t)(t % GX) * 128;

    int lrow8  = lane >> 3;
    int lchunk = (lane & 7) ^ lrow8;
    const __bf16* Ag0 = A  + (rowBase + wid * 32 + lrow8) * (size_t)K + lchunk * 8;
    const __bf16* Bg0 = Bt + (colBase + wid * 32 + lrow8) * (size_t)K + lchunk * 8;
    __bf16* AsB = &As[(wid * 32) * 64];
    __bf16* BsB = &Bs[(wid * 32) * 64];

    f32x4 acc[4][4] = {};
    int swz = l15 & 7;

    for (int kb = 0; kb < K; kb += 64) {
        __syncthreads();
        #pragma unroll
        for (int i = 0; i < 4; i++) {
            gll16(Ag0 + (size_t)i * 8 * K + kb, AsB + i * 512);
            gll16(Bg0 + (size_t)i * 8 * K + kb, BsB + i * 512);
        }
        __syncthreads();
        #pragma unroll
        for (int ks = 0; ks < 2; ks++) {
            int p = ((ks * 4 + quad) ^ swz) * 8;
            bf16x8 af[4], bfr[4];
            #pragma unroll
            for (int mi = 0; mi < 4; mi++)
                af[mi] = *(const bf16x8*)&As[(waveM * 64 + mi * 16 + l15) * 64 + p];
            #pragma unroll
            for (int ni = 0; ni < 4; ni++)
                bfr[ni] = *(const bf16x8*)&Bs[(waveN * 64 + ni * 16 + l15) * 64 + p];
            #pragma unroll
            for (int mi = 0; mi < 4; mi++)
                #pragma unroll
                for (int ni = 0; ni < 4; ni++)
                    acc[mi][ni] = __builtin_amdgcn_mfma_f32_16x16x32_bf16(
                        af[mi], bfr[ni], acc[mi][ni], 0, 0, 0);
        }
    }

    #pragma unroll
    for (int mi = 0; mi < 4; mi++)
    #pragma unroll
    for (int ni = 0; ni < 4; ni++) {
        size_t col = colBase + waveN * 64 + ni * 16 + l15;        // dim in E
        size_t m0  = rowBase + waveM * 64 + mi * 16 + quad * 4;   // token
        bf16x4 pk;
        #pragma unroll
        for (int r = 0; r < 4; r++) pk[r] = (__bf16)acc[mi][ni][r];
        *(bf16x4*)&Cout[col * M + m0] = pk;
    }
}

// ---------------------------------------------------------------------------
// Flash attention, transposed-score formulation, 512 threads (8 waves x 16 q).
// Q side of QKb is pre-scaled by (1/8)*log2(e) so softmax uses raw exp2.
// PV uses 16x16x16 MFMA (no cross-lane shuffles). V is reg-staged into LDS
// with a field-swap unit permutation: global 8B unit u=4*nt+quad stored at
// position p=4*quad+nt (16B chunks XOR-swizzled by row&7), so each lane's
// four PV fragments are contiguous -> 2x ds_read_b128 per dt, static halves.
// ---------------------------------------------------------------------------
__global__ __launch_bounds__(512, 6) void attn_kernel(const __bf16* __restrict__ QK,
                                                      const __bf16* __restrict__ Vt,
                                                      const int* __restrict__ mask,
                                                      __bf16* __restrict__ Out) {
    const int S = 2048, E = 1024, E2 = 2048, M = 8192;
    int qt = blockIdx.x, bh = blockIdx.y;
    int b = bh >> 4, h = bh & 15;
    int q0 = qt * 128;
    int tid = threadIdx.x, lane = tid & 63, wid = tid >> 6;  // wid 0..7
    int quad = lane >> 4, l15 = lane & 15;

    __shared__ __bf16 Ks[2][4096];
    __shared__ __bf16 Vs[2][4096];

    bf16x8 aq[2];
    #pragma unroll
    for (int hh = 0; hh < 2; hh++) {
        size_t row = (size_t)(b * S + q0 + wid * 16 + l15);
        aq[hh] = *(const bf16x8*)(QK + row * E2 + h * 64 + hh * 32 + quad * 8);
    }

    int lrow8  = lane >> 3;
    int lchunk = (lane & 7) ^ lrow8;
    const __bf16* Kg0 = QK + (size_t)(b * S + wid * 8 + lrow8) * E2 + 1024 + h * 64 + lchunk * 8;

    // V reg-staging: thread (rv, cv) loads global 16B chunk cv of V^T row rv.
    int rv = tid >> 3, cv = tid & 7;
    const __bf16* Vg0 = Vt + (size_t)(h * 64 + rv) * M + b * S + cv * 8;
    // store offsets: global unit u=2cv+h -> position p=4*(u&3)+(u>>2);
    // 16B-chunk (p>>1) ^ (row&7), low-bit p&1 selects 8B half.
    int c0   = ((cv & 1) << 2) + (cv >> 2);
    int lowb = (cv >> 1) & 1;
    int sv   = rv & 7;
    int wo0  = rv * 64 + ((c0 ^ sv) << 3) + (lowb << 2);
    int wo1  = rv * 64 + ((((c0 + 2)) ^ sv) << 3) + (lowb << 2);

    int swz = l15 & 7;

    f32x4 accO[4] = {};
    f32x2 acc2 = {0.f, 0.f};

    bf16x8 vreg = *(const bf16x8*)(Vg0);
    gll16(Kg0, &Ks[0][wid * 512]);
    {
        *(bf16x4*)&Vs[0][wo0] = __builtin_shufflevector(vreg, vreg, 0, 1, 2, 3);
        *(bf16x4*)&Vs[0][wo1] = __builtin_shufflevector(vreg, vreg, 4, 5, 6, 7);
    }
    __syncthreads();

    for (int kt = 0; kt < S / 64; kt++) {
        int k0 = kt * 64;
        int buf = kt & 1;
        if (kt + 1 < S / 64) {
            vreg = *(const bf16x8*)(Vg0 + k0 + 64);            // issue early (T14)
            gll16(Kg0 + (size_t)(k0 + 64) * E2, &Ks[buf ^ 1][wid * 512]);
        }
        const __bf16* Ksb = &Ks[buf][0];
        const __bf16* Vsb = &Vs[buf][0];

        f32x4 sa[4];
        #pragma unroll
        for (int nt = 0; nt < 4; nt++) {
            bf16x8 a0 = *(const bf16x8*)&Ksb[(nt * 16 + l15) * 64 + ((quad) ^ swz) * 8];
            bf16x8 a1 = *(const bf16x8*)&Ksb[(nt * 16 + l15) * 64 + ((4 + quad) ^ swz) * 8];
            f32x4 a = {};
            a = __builtin_amdgcn_mfma_f32_16x16x32_bf16(a0, aq[0], a, 0, 0, 0);
            a = __builtin_amdgcn_mfma_f32_16x16x32_bf16(a1, aq[1], a, 0, 0, 0);
            sa[nt] = a;
        }

        bf16x4 pb[4];
        #pragma unroll
        for (int nt = 0; nt < 4; nt++) {
            int4 mz = *(const int4*)&mask[b * S + k0 + nt * 16 + quad * 4];
            float p0 = mz.x ? EXP2(sa[nt][0]) : 0.f;
            float p1 = mz.y ? EXP2(sa[nt][1]) : 0.f;
            float p2 = mz.z ? EXP2(sa[nt][2]) : 0.f;
            float p3 = mz.w ? EXP2(sa[nt][3]) : 0.f;
            f32x2 t01; t01[0] = p0; t01[1] = p1;
            f32x2 t23; t23[0] = p2; t23[1] = p3;
            acc2 += t01 + t23;
            bf16x4 pk;
            pk[0] = (__bf16)p0; pk[1] = (__bf16)p1;
            pk[2] = (__bf16)p2; pk[3] = (__bf16)p3;
            pb[nt] = pk;
        }

        // PV: 2x b128 per dt; halves are nt fragments (static extract).
        #pragma unroll
        for (int dt = 0; dt < 4; dt++) {
            const __bf16* vrow = &Vsb[(dt * 16 + l15) * 64];
            bf16x8 vv0 = *(const bf16x8*)&vrow[((quad * 2 + 0) ^ swz) * 8];
            bf16x8 vv1 = *(const bf16x8*)&vrow[((quad * 2 + 1) ^ swz) * 8];
            accO[dt] = mfma16x16(__builtin_shufflevector(vv0, vv0, 0, 1, 2, 3), pb[0], accO[dt]);
            accO[dt] = mfma16x16(__builtin_shufflevector(vv0, vv0, 4, 5, 6, 7), pb[1], accO[dt]);
            accO[dt] = mfma16x16(__builtin_shufflevector(vv1, vv1, 0, 1, 2, 3), pb[2], accO[dt]);
            accO[dt] = mfma16x16(__builtin_shufflevector(vv1, vv1, 4, 5, 6, 7), pb[3], accO[dt]);
        }

        if (kt + 1 < S / 64) {
            // write-late half of the async stage (vmcnt wait lands here)
            *(bf16x4*)&Vs[buf ^ 1][wo0] = __builtin_shufflevector(vreg, vreg, 0, 1, 2, 3);
            *(bf16x4*)&Vs[buf ^ 1][wo1] = __builtin_shufflevector(vreg, vreg, 4, 5, 6, 7);
        }
        __syncthreads();
    }

    float l = acc2[0] + acc2[1];
    l += __shfl_xor(l, 16, 64);
    l += __shfl_xor(l, 32, 64);
    float inv = 1.0f / l;

    #pragma unroll
    for (int dt = 0; dt < 4; dt++) {
        size_t row = (size_t)(b * S + q0 + wid * 16 + l15);
        bf16x4 pk;
        #pragma unroll
        for (int r = 0; r < 4; r++) pk[r] = (__bf16)(accO[dt][r] * inv);
        *(bf16x4*)&Out[row * E + h * 64 + dt * 16 + quad * 4] = pk;
    }
}

// ---------------------------------------------------------------------------
// Launch
// ---------------------------------------------------------------------------
extern "C" void kernel_launch(void* const* d_in, const int* in_sizes, int n_in,
                              void* d_out, int out_size, void* d_ws, size_t ws_size,
                              hipStream_t stream) {
    const int Bb = 4, S = 2048, E = 1024, FF = 4096;
    const int M = Bb * S;  // 8192

    const float* value = (const float*)d_in[0];
    const float* key   = (const float*)d_in[1];
    const float* query = (const float*)d_in[2];
    const int*   mask  = (const int*)d_in[3];
    const float* Wv    = (const float*)d_in[4];
    const float* Wk    = (const float*)d_in[5];
    const float* Wq    = (const float*)d_in[6];
    const float* Wo    = (const float*)d_in[7];
    const float* bo    = (const float*)d_in[8];
    const float* ln1_g = (const float*)d_in[9];
    const float* ln1_b = (const float*)d_in[10];
    const float* ln2_g = (const float*)d_in[11];
    const float* ln2_b = (const float*)d_in[12];
    const float* lnf_g = (const float*)d_in[13];
    const float* lnf_b = (const float*)d_in[14];
    const float* W1    = (const float*)d_in[15];
    const float* b1    = (const float*)d_in[16];
    const float* W2    = (const float*)d_in[17];
    const float* b2    = (const float*)d_in[18];

    char* ws = (char*)d_ws;
    const size_t MB = 1024 * 1024;
    __bf16* Wqt = (__bf16*)(ws + 0 * MB);
    __bf16* Wkt = (__bf16*)(ws + 2 * MB);
    __bf16* Wvt = (__bf16*)(ws + 4 * MB);
    __bf16* Wot = (__bf16*)(ws + 6 * MB);
    __bf16* W1t = (__bf16*)(ws + 8 * MB);    // [FF, E]
    __bf16* W2t = (__bf16*)(ws + 16 * MB);   // [E, FF]
    __bf16* q_bf = (__bf16*)(ws + 24 * MB);
    __bf16* k_bf = (__bf16*)(ws + 40 * MB);
    __bf16* v_bf = (__bf16*)(ws + 56 * MB);
    __bf16* QKb  = (__bf16*)(ws + 72 * MB);  // [M, 2E]
    __bf16* Vtg  = (__bf16*)(ws + 104 * MB); // V^T [E, M]
    __bf16* attn = q_bf;
    __bf16* x_ln = k_bf;
    __bf16* h1   = v_bf;                     // [M, FF] 64MB
    float*  qln  = (float*)(ws + 120 * MB);
    float*  x32  = (float*)(ws + 152 * MB);

    transpose_all<<<12288, 256, 0, stream>>>(Wq, Wk, Wv, Wo, W1, W2,
                                             Wqt, Wkt, Wvt, Wot, W1t, W2t);

    ln3_kernel<<<dim3(M, 3), 256, 0, stream>>>(query, key, value,
                                               ln1_g, ln1_b, ln2_g, ln2_b,
                                               qln, q_bf, k_bf, v_bf);

    // merged Q|K projection -> QKb [M, 2E]; Q side scaled (1/8)*log2(e).
    gemm128<0><<<16 * 64, 256, 0, stream>>>(
        q_bf, k_bf, Wqt, Wkt, nullptr, nullptr, QKb, M, 2 * E, E, E,
        0.125f * 1.44269504088896f);

    // V projection -> V^T [E, M]. grid 8*64.
    gemmV<<<8 * 64, 256, 0, stream>>>(v_bf, Wvt, Vtg, M, E, E);

    attn_kernel<<<dim3(S / 128, Bb * 16), 512, 0, stream>>>(QKb, Vtg, mask, attn);

    // out proj + bias + residual(qln) -> x32 (f32). grid 8*64.
    gemm128<1><<<8 * 64, 256, 0, stream>>>(
        attn, attn, Wot, Wot, bo, qln, x32, M, E, E, E, 1.0f);

    ln_kernel<<<M, 256, 0, stream>>>(x32, lnf_g, lnf_b, x_ln);

    // FFN1: grid 32*64.
    gemm128<2><<<32 * 64, 256, 0, stream>>>(
        x_ln, x_ln, W1t, W1t, b1, nullptr, h1, M, FF, E, FF, 1.0f);
    // FFN2: grid 8*64.
    gemm128<1><<<8 * 64, 256, 0, stream>>>(
        h1, h1, W2t, W2t, b2, x32, (float*)d_out, M, E, FF, E, 1.0f);
}

// Round 5
// 652.884 us; speedup vs baseline: 1.0549x; 1.0250x over previous
//
#include <hip/hip_runtime.h>
#include <hip/hip_bf16.h>
#include <math.h>

typedef __bf16 bf16x8 __attribute__((ext_vector_type(8)));
typedef __bf16 bf16x4 __attribute__((ext_vector_type(4)));
typedef float f32x4 __attribute__((ext_vector_type(4)));
typedef float f32x2 __attribute__((ext_vector_type(2)));
typedef short s16x4 __attribute__((ext_vector_type(4)));

#define AS1 __attribute__((address_space(1)))
#define AS3 __attribute__((address_space(3)))

__device__ __forceinline__ void gll16(const __bf16* g, __bf16* l) {
    __builtin_amdgcn_global_load_lds((const AS1 unsigned int*)g,
                                     (AS3 unsigned int*)l, 16, 0, 0);
}

#if __has_builtin(__builtin_amdgcn_exp2f)
#define EXP2(x) __builtin_amdgcn_exp2f(x)
#else
#define EXP2(x) __expf((x) * 0.69314718055994530942f)
#endif

// PV matmul with K=16 MFMA: B-operand layout (lane holds B[k=quad*4+j][q=l15])
// matches the QK^T score output layout exactly -> no cross-lane shuffle.
__device__ __forceinline__ f32x4 mfma16x16(bf16x4 a, bf16x4 b, f32x4 c) {
#if __has_builtin(__builtin_amdgcn_mfma_f32_16x16x16bf16_1k)
    union { bf16x4 h; s16x4 s; } ua, ub;
    ua.h = a; ub.h = b;
    return __builtin_amdgcn_mfma_f32_16x16x16bf16_1k(ua.s, ub.s, c, 0, 0, 0);
#else
    f32x4 d = c;
    asm volatile("v_mfma_f32_16x16x16_bf16 %0, %1, %2, %0"
                 : "+v"(d) : "v"(a), "v"(b));
    return d;
#endif
}

// ---------------------------------------------------------------------------
// All 6 weight transposes (fp32 [K,N] -> bf16 [N,K]) in one launch.
// ---------------------------------------------------------------------------
__global__ __launch_bounds__(256) void transpose_all(
    const float* __restrict__ Wq, const float* __restrict__ Wk,
    const float* __restrict__ Wv, const float* __restrict__ Wo,
    const float* __restrict__ W1, const float* __restrict__ W2,
    __bf16* __restrict__ Wqt, __bf16* __restrict__ Wkt,
    __bf16* __restrict__ Wvt, __bf16* __restrict__ Wot,
    __bf16* __restrict__ W1t, __bf16* __restrict__ W2t) {
    int g = blockIdx.x;
    const float* W; __bf16* Wt; int K, N, kt, nt;
    if (g < 4096) {
        int mi = g >> 10, loc = g & 1023;
        K = 1024; N = 1024; kt = loc >> 5; nt = loc & 31;
        W  = mi == 0 ? Wq  : mi == 1 ? Wk  : mi == 2 ? Wv  : Wo;
        Wt = mi == 0 ? Wqt : mi == 1 ? Wkt : mi == 2 ? Wvt : Wot;
    } else if (g < 8192) {
        int loc = g - 4096; W = W1; Wt = W1t;
        K = 1024; N = 4096; kt = loc >> 7; nt = loc & 127;
    } else {
        int loc = g - 8192; W = W2; Wt = W2t;
        K = 4096; N = 1024; kt = loc >> 5; nt = loc & 31;
    }
    int k0 = kt * 32, n0 = nt * 32;
    __shared__ float tile[32][33];
    int tx = threadIdx.x & 31, ty = threadIdx.x >> 5;
    #pragma unroll
    for (int j = ty; j < 32; j += 8)
        tile[j][tx] = W[(size_t)(k0 + j) * N + n0 + tx];
    __syncthreads();
    #pragma unroll
    for (int j = ty; j < 32; j += 8)
        Wt[(size_t)(n0 + j) * K + k0 + tx] = (__bf16)tile[tx][j];
}

// ---------------------------------------------------------------------------
// Fused 3-way pre-norm.
// ---------------------------------------------------------------------------
__global__ __launch_bounds__(256) void ln3_kernel(
    const float* __restrict__ q, const float* __restrict__ k,
    const float* __restrict__ v,
    const float* __restrict__ g1, const float* __restrict__ b1,
    const float* __restrict__ g2, const float* __restrict__ b2,
    float* __restrict__ qln, __bf16* __restrict__ qbf,
    __bf16* __restrict__ kbf, __bf16* __restrict__ vbf) {
    const int E = 1024;
    int which = blockIdx.y;
    const float* x = which == 0 ? q : which == 1 ? k : v;
    const float* g = which == 0 ? g1 : g2;
    const float* bb = which == 0 ? b1 : b2;
    float* o32 = which == 0 ? qln : nullptr;
    __bf16* obf = which == 0 ? qbf : which == 1 ? kbf : vbf;

    size_t row = blockIdx.x;
    int t = threadIdx.x;
    float4 val = ((const float4*)(x + row * E))[t];
    float s  = val.x + val.y + val.z + val.w;
    float s2 = val.x * val.x + val.y * val.y + val.z * val.z + val.w * val.w;
    #pragma unroll
    for (int off = 32; off >= 1; off >>= 1) {
        s  += __shfl_down(s, off);
        s2 += __shfl_down(s2, off);
    }
    __shared__ float red[2][4];
    int wid = t >> 6, lane = t & 63;
    if (lane == 0) { red[0][wid] = s; red[1][wid] = s2; }
    __syncthreads();
    if (t == 0) {
        float S1 = red[0][0] + red[0][1] + red[0][2] + red[0][3];
        float S2 = red[1][0] + red[1][1] + red[1][2] + red[1][3];
        float mean = S1 / E;
        float var  = S2 / E - mean * mean;
        red[0][0] = mean;
        red[1][0] = 1.0f / sqrtf(var + 1e-5f);
    }
    __syncthreads();
    float mean = red[0][0], rstd = red[1][0];
    float4 gv = ((const float4*)g)[t];
    float4 bv = ((const float4*)bb)[t];
    float y0 = (val.x - mean) * rstd * gv.x + bv.x;
    float y1 = (val.y - mean) * rstd * gv.y + bv.y;
    float y2 = (val.z - mean) * rstd * gv.z + bv.z;
    float y3 = (val.w - mean) * rstd * gv.w + bv.w;
    if (o32) ((float4*)(o32 + row * E))[t] = make_float4(y0, y1, y2, y3);
    bf16x4 o;
    o[0] = (__bf16)y0; o[1] = (__bf16)y1; o[2] = (__bf16)y2; o[3] = (__bf16)y3;
    ((bf16x4*)(obf + row * E))[t] = o;
}

// single-input LN (final norm), bf16 out
__global__ __launch_bounds__(256) void ln_kernel(const float* __restrict__ x,
                                                 const float* __restrict__ g,
                                                 const float* __restrict__ bb,
                                                 __bf16* __restrict__ outbf) {
    const int E = 1024;
    size_t row = blockIdx.x;
    int t = threadIdx.x;
    float4 v = ((const float4*)(x + row * E))[t];
    float s  = v.x + v.y + v.z + v.w;
    float s2 = v.x * v.x + v.y * v.y + v.z * v.z + v.w * v.w;
    #pragma unroll
    for (int off = 32; off >= 1; off >>= 1) {
        s  += __shfl_down(s, off);
        s2 += __shfl_down(s2, off);
    }
    __shared__ float red[2][4];
    int wid = t >> 6, lane = t & 63;
    if (lane == 0) { red[0][wid] = s; red[1][wid] = s2; }
    __syncthreads();
    if (t == 0) {
        float S1 = red[0][0] + red[0][1] + red[0][2] + red[0][3];
        float S2 = red[1][0] + red[1][1] + red[1][2] + red[1][3];
        float mean = S1 / E;
        float var  = S2 / E - mean * mean;
        red[0][0] = mean;
        red[1][0] = 1.0f / sqrtf(var + 1e-5f);
    }
    __syncthreads();
    float mean = red[0][0], rstd = red[1][0];
    float4 gv = ((const float4*)g)[t];
    float4 bv = ((const float4*)bb)[t];
    bf16x4 o;
    o[0] = (__bf16)((v.x - mean) * rstd * gv.x + bv.x);
    o[1] = (__bf16)((v.y - mean) * rstd * gv.y + bv.y);
    o[2] = (__bf16)((v.z - mean) * rstd * gv.z + bv.z);
    o[3] = (__bf16)((v.w - mean) * rstd * gv.w + bv.w);
    ((bf16x4*)(outbf + row * E))[t] = o;
}

// ---------------------------------------------------------------------------
// GEMM 128x128 tile, 1D grid with XCD row-affinity swizzle.
// Swapped-operand MFMA (C^T accum layout: lane row=l15, col=quad*4+r).
// Column split at splitN selects (A2,Bt2) for merged QK.
// EPI: 0 bf16*sc out; 1 f32+bias+resid; 2 bf16+bias+gelu.
// ---------------------------------------------------------------------------
template <int EPI>
__global__ __launch_bounds__(256) void gemm128(const __bf16* __restrict__ A,
                                               const __bf16* __restrict__ A2,
                                               const __bf16* __restrict__ Bt,
                                               const __bf16* __restrict__ Bt2,
                                               const float* __restrict__ bias,
                                               const float* __restrict__ resid,
                                               void* __restrict__ Cout,
                                               int M, int N, int K,
                                               int splitN, float scale) {
    __shared__ __bf16 As[128 * 64];
    __shared__ __bf16 Bs[128 * 64];
    int tid  = threadIdx.x;
    int lane = tid & 63, wid = tid >> 6;
    int quad = lane >> 4, l15 = lane & 15;
    int waveM = wid >> 1, waveN = wid & 1;

    int GX = N >> 7;
    int id = blockIdx.x;
    int x8 = id & 7, t = id >> 3;
    size_t rowBase = (size_t)((t / GX) * 8 + x8) * 128;
    size_t colBase = (size_t)(t % GX) * 128;

    const __bf16* Ap = A; const __bf16* Bp = Bt;
    size_t colLoc = colBase;
    float sc = scale;
    if ((int)colBase >= splitN) { Ap = A2; Bp = Bt2; colLoc = colBase - splitN; sc = 1.0f; }

    int lrow8  = lane >> 3;
    int lchunk = (lane & 7) ^ lrow8;
    const __bf16* Ag0 = Ap + (rowBase + wid * 32 + lrow8) * (size_t)K + lchunk * 8;
    const __bf16* Bg0 = Bp + (colLoc  + wid * 32 + lrow8) * (size_t)K + lchunk * 8;
    __bf16* AsB = &As[(wid * 32) * 64];
    __bf16* BsB = &Bs[(wid * 32) * 64];

    f32x4 acc[4][4] = {};
    int swz = l15 & 7;

    for (int kb = 0; kb < K; kb += 64) {
        __syncthreads();
        #pragma unroll
        for (int i = 0; i < 4; i++) {
            gll16(Ag0 + (size_t)i * 8 * K + kb, AsB + i * 512);
            gll16(Bg0 + (size_t)i * 8 * K + kb, BsB + i * 512);
        }
        __syncthreads();
        #pragma unroll
        for (int ks = 0; ks < 2; ks++) {
            int p = ((ks * 4 + quad) ^ swz) * 8;
            bf16x8 af[4], bfr[4];
            #pragma unroll
            for (int mi = 0; mi < 4; mi++)
                af[mi] = *(const bf16x8*)&As[(waveM * 64 + mi * 16 + l15) * 64 + p];
            #pragma unroll
            for (int ni = 0; ni < 4; ni++)
                bfr[ni] = *(const bf16x8*)&Bs[(waveN * 64 + ni * 16 + l15) * 64 + p];
            #pragma unroll
            for (int mi = 0; mi < 4; mi++)
                #pragma unroll
                for (int ni = 0; ni < 4; ni++)
                    acc[mi][ni] = __builtin_amdgcn_mfma_f32_16x16x32_bf16(
                        bfr[ni], af[mi], acc[mi][ni], 0, 0, 0);  // swapped: C^T
        }
    }

    #pragma unroll
    for (int mi = 0; mi < 4; mi++)
    #pragma unroll
    for (int ni = 0; ni < 4; ni++) {
        size_t row = rowBase + waveM * 64 + mi * 16 + l15;
        size_t col = colBase + waveN * 64 + ni * 16 + quad * 4;
        f32x4 v = acc[mi][ni];
        if (EPI == 1) {
            float4 b4 = *(const float4*)&bias[col];
            float4 r4 = *(const float4*)&resid[row * N + col];
            float4 o;
            o.x = v[0] + b4.x + r4.x; o.y = v[1] + b4.y + r4.y;
            o.z = v[2] + b4.z + r4.z; o.w = v[3] + b4.w + r4.w;
            *(float4*)&((float*)Cout)[row * N + col] = o;
        } else if (EPI == 2) {
            float4 b4 = *(const float4*)&bias[col];
            bf16x4 pk;
            #pragma unroll
            for (int r = 0; r < 4; r++) {
                float t2 = v[r] + ((const float*)&b4)[r];
                pk[r] = (__bf16)(0.5f * t2 * (1.0f + erff(t2 * 0.70710678118654752f)));
            }
            *(bf16x4*)&((__bf16*)Cout)[row * N + col] = pk;
        } else {
            bf16x4 pk;
            #pragma unroll
            for (int r = 0; r < 4; r++) pk[r] = (__bf16)(v[r] * sc);
            *(bf16x4*)&((__bf16*)Cout)[row * N + col] = pk;
        }
    }
}

// ---------------------------------------------------------------------------
// V projection GEMM (non-swapped MFMA) writing V^T [E, M], packed stores.
// ---------------------------------------------------------------------------
__global__ __launch_bounds__(256) void gemmV(const __bf16* __restrict__ A,
                                             const __bf16* __restrict__ Bt,
                                             __bf16* __restrict__ Cout,
                                             int M, int N, int K) {
    __shared__ __bf16 As[128 * 64];
    __shared__ __bf16 Bs[128 * 64];
    int tid  = threadIdx.x;
    int lane = tid & 63, wid = tid >> 6;
    int quad = lane >> 4, l15 = lane & 15;
    int waveM = wid >> 1, waveN = wid & 1;

    int GX = N >> 7;
    int id = blockIdx.x;
    int x8 = id & 7, t = id >> 3;
    size_t rowBase = (size_t)((t / GX) * 8 + x8) * 128;
    size_t colBase = (size_t)(t % GX) * 128;

    int lrow8  = lane >> 3;
    int lchunk = (lane & 7) ^ lrow8;
    const __bf16* Ag0 = A  + (rowBase + wid * 32 + lrow8) * (size_t)K + lchunk * 8;
    const __bf16* Bg0 = Bt + (colBase + wid * 32 + lrow8) * (size_t)K + lchunk * 8;
    __bf16* AsB = &As[(wid * 32) * 64];
    __bf16* BsB = &Bs[(wid * 32) * 64];

    f32x4 acc[4][4] = {};
    int swz = l15 & 7;

    for (int kb = 0; kb < K; kb += 64) {
        __syncthreads();
        #pragma unroll
        for (int i = 0; i < 4; i++) {
            gll16(Ag0 + (size_t)i * 8 * K + kb, AsB + i * 512);
            gll16(Bg0 + (size_t)i * 8 * K + kb, BsB + i * 512);
        }
        __syncthreads();
        #pragma unroll
        for (int ks = 0; ks < 2; ks++) {
            int p = ((ks * 4 + quad) ^ swz) * 8;
            bf16x8 af[4], bfr[4];
            #pragma unroll
            for (int mi = 0; mi < 4; mi++)
                af[mi] = *(const bf16x8*)&As[(waveM * 64 + mi * 16 + l15) * 64 + p];
            #pragma unroll
            for (int ni = 0; ni < 4; ni++)
                bfr[ni] = *(const bf16x8*)&Bs[(waveN * 64 + ni * 16 + l15) * 64 + p];
            #pragma unroll
            for (int mi = 0; mi < 4; mi++)
                #pragma unroll
                for (int ni = 0; ni < 4; ni++)
                    acc[mi][ni] = __builtin_amdgcn_mfma_f32_16x16x32_bf16(
                        af[mi], bfr[ni], acc[mi][ni], 0, 0, 0);
        }
    }

    #pragma unroll
    for (int mi = 0; mi < 4; mi++)
    #pragma unroll
    for (int ni = 0; ni < 4; ni++) {
        size_t col = colBase + waveN * 64 + ni * 16 + l15;        // dim in E
        size_t m0  = rowBase + waveM * 64 + mi * 16 + quad * 4;   // token
        bf16x4 pk;
        #pragma unroll
        for (int r = 0; r < 4; r++) pk[r] = (__bf16)acc[mi][ni][r];
        *(bf16x4*)&Cout[col * M + m0] = pk;
    }
}

// ---------------------------------------------------------------------------
// Flash attention, transposed-score formulation, 512 threads (8 waves).
// Each wave owns 32 q-rows (2 groups of 16): every K/V fragment read from
// LDS feeds TWO q-groups -> LDS-read bytes per MFMA halve (LDS-BW was the
// measured bottleneck: MfmaUtil 31% == 16KB/wave-tile @256B/cy model).
// Q side of QKb is pre-scaled by (1/8)*log2(e) so softmax uses raw exp2.
// PV uses 16x16x16 MFMA (no cross-lane shuffles). V is reg-staged into LDS
// with a field-swap unit permutation: global 8B unit u=4*nt+quad stored at
// position p=4*quad+nt (16B chunks XOR-swizzled by row&7), so each lane's
// four PV fragments are contiguous -> 2x ds_read_b128 per dt, static halves.
// ---------------------------------------------------------------------------
__global__ __launch_bounds__(512, 4) void attn_kernel(const __bf16* __restrict__ QK,
                                                      const __bf16* __restrict__ Vt,
                                                      const int* __restrict__ mask,
                                                      __bf16* __restrict__ Out) {
    const int S = 2048, E = 1024, E2 = 2048, M = 8192;
    int qt = blockIdx.x, bh = blockIdx.y;
    int b = bh >> 4, h = bh & 15;
    int q0 = qt * 256;
    int tid = threadIdx.x, lane = tid & 63, wid = tid >> 6;  // wid 0..7
    int quad = lane >> 4, l15 = lane & 15;

    __shared__ __bf16 Ks[2][4096];
    __shared__ __bf16 Vs[2][4096];

    bf16x8 aq[2][2];
    #pragma unroll
    for (int g = 0; g < 2; g++)
    #pragma unroll
    for (int hh = 0; hh < 2; hh++) {
        size_t row = (size_t)(b * S + q0 + wid * 32 + g * 16 + l15);
        aq[g][hh] = *(const bf16x8*)(QK + row * E2 + h * 64 + hh * 32 + quad * 8);
    }

    int lrow8  = lane >> 3;
    int lchunk = (lane & 7) ^ lrow8;
    const __bf16* Kg0 = QK + (size_t)(b * S + wid * 8 + lrow8) * E2 + 1024 + h * 64 + lchunk * 8;

    // V reg-staging: thread (rv, cv) loads global 16B chunk cv of V^T row rv.
    int rv = tid >> 3, cv = tid & 7;
    const __bf16* Vg0 = Vt + (size_t)(h * 64 + rv) * M + b * S + cv * 8;
    int c0   = ((cv & 1) << 2) + (cv >> 2);
    int lowb = (cv >> 1) & 1;
    int sv   = rv & 7;
    int wo0  = rv * 64 + ((c0 ^ sv) << 3) + (lowb << 2);
    int wo1  = rv * 64 + (((c0 + 2) ^ sv) << 3) + (lowb << 2);

    int swz = l15 & 7;

    f32x4 accO[2][4] = {};
    f32x2 acc2[2] = {};

    bf16x8 vreg = *(const bf16x8*)(Vg0);
    gll16(Kg0, &Ks[0][wid * 512]);
    *(bf16x4*)&Vs[0][wo0] = __builtin_shufflevector(vreg, vreg, 0, 1, 2, 3);
    *(bf16x4*)&Vs[0][wo1] = __builtin_shufflevector(vreg, vreg, 4, 5, 6, 7);
    __syncthreads();

    for (int kt = 0; kt < S / 64; kt++) {
        int k0 = kt * 64;
        int buf = kt & 1;
        if (kt + 1 < S / 64) {
            vreg = *(const bf16x8*)(Vg0 + k0 + 64);            // issue early (T14)
            gll16(Kg0 + (size_t)(k0 + 64) * E2, &Ks[buf ^ 1][wid * 512]);
        }
        const __bf16* Ksb = &Ks[buf][0];
        const __bf16* Vsb = &Vs[buf][0];

        bf16x4 pb[2][4];
        #pragma unroll
        for (int nt = 0; nt < 4; nt++) {
            bf16x8 a0 = *(const bf16x8*)&Ksb[(nt * 16 + l15) * 64 + ((quad) ^ swz) * 8];
            bf16x8 a1 = *(const bf16x8*)&Ksb[(nt * 16 + l15) * 64 + ((4 + quad) ^ swz) * 8];
            int4 mz = *(const int4*)&mask[b * S + k0 + nt * 16 + quad * 4];
            #pragma unroll
            for (int g = 0; g < 2; g++) {
                f32x4 a = {};
                a = __builtin_amdgcn_mfma_f32_16x16x32_bf16(a0, aq[g][0], a, 0, 0, 0);
                a = __builtin_amdgcn_mfma_f32_16x16x32_bf16(a1, aq[g][1], a, 0, 0, 0);
                float p0 = mz.x ? EXP2(a[0]) : 0.f;
                float p1 = mz.y ? EXP2(a[1]) : 0.f;
                float p2 = mz.z ? EXP2(a[2]) : 0.f;
                float p3 = mz.w ? EXP2(a[3]) : 0.f;
                f32x2 t01; t01[0] = p0; t01[1] = p1;
                f32x2 t23; t23[0] = p2; t23[1] = p3;
                acc2[g] += t01 + t23;
                bf16x4 pk;
                pk[0] = (__bf16)p0; pk[1] = (__bf16)p1;
                pk[2] = (__bf16)p2; pk[3] = (__bf16)p3;
                pb[g][nt] = pk;
            }
        }

        // PV: 2x b128 per dt; halves are nt fragments, shared by both groups.
        #pragma unroll
        for (int dt = 0; dt < 4; dt++) {
            const __bf16* vrow = &Vsb[(dt * 16 + l15) * 64];
            bf16x8 vv0 = *(const bf16x8*)&vrow[((quad * 2 + 0) ^ swz) * 8];
            bf16x8 vv1 = *(const bf16x8*)&vrow[((quad * 2 + 1) ^ swz) * 8];
            bf16x4 h00 = __builtin_shufflevector(vv0, vv0, 0, 1, 2, 3);
            bf16x4 h01 = __builtin_shufflevector(vv0, vv0, 4, 5, 6, 7);
            bf16x4 h10 = __builtin_shufflevector(vv1, vv1, 0, 1, 2, 3);
            bf16x4 h11 = __builtin_shufflevector(vv1, vv1, 4, 5, 6, 7);
            #pragma unroll
            for (int g = 0; g < 2; g++) {
                accO[g][dt] = mfma16x16(h00, pb[g][0], accO[g][dt]);
                accO[g][dt] = mfma16x16(h01, pb[g][1], accO[g][dt]);
                accO[g][dt] = mfma16x16(h10, pb[g][2], accO[g][dt]);
                accO[g][dt] = mfma16x16(h11, pb[g][3], accO[g][dt]);
            }
        }

        if (kt + 1 < S / 64) {
            // write-late half of the async stage (vmcnt wait lands here)
            *(bf16x4*)&Vs[buf ^ 1][wo0] = __builtin_shufflevector(vreg, vreg, 0, 1, 2, 3);
            *(bf16x4*)&Vs[buf ^ 1][wo1] = __builtin_shufflevector(vreg, vreg, 4, 5, 6, 7);
        }
        __syncthreads();
    }

    #pragma unroll
    for (int g = 0; g < 2; g++) {
        float l = acc2[g][0] + acc2[g][1];
        l += __shfl_xor(l, 16, 64);
        l += __shfl_xor(l, 32, 64);
        float inv = 1.0f / l;
        #pragma unroll
        for (int dt = 0; dt < 4; dt++) {
            size_t row = (size_t)(b * S + q0 + wid * 32 + g * 16 + l15);
            bf16x4 pk;
            #pragma unroll
            for (int r = 0; r < 4; r++) pk[r] = (__bf16)(accO[g][dt][r] * inv);
            *(bf16x4*)&Out[row * E + h * 64 + dt * 16 + quad * 4] = pk;
        }
    }
}

// ---------------------------------------------------------------------------
// Launch
// ---------------------------------------------------------------------------
extern "C" void kernel_launch(void* const* d_in, const int* in_sizes, int n_in,
                              void* d_out, int out_size, void* d_ws, size_t ws_size,
                              hipStream_t stream) {
    const int Bb = 4, S = 2048, E = 1024, FF = 4096;
    const int M = Bb * S;  // 8192

    const float* value = (const float*)d_in[0];
    const float* key   = (const float*)d_in[1];
    const float* query = (const float*)d_in[2];
    const int*   mask  = (const int*)d_in[3];
    const float* Wv    = (const float*)d_in[4];
    const float* Wk    = (const float*)d_in[5];
    const float* Wq    = (const float*)d_in[6];
    const float* Wo    = (const float*)d_in[7];
    const float* bo    = (const float*)d_in[8];
    const float* ln1_g = (const float*)d_in[9];
    const float* ln1_b = (const float*)d_in[10];
    const float* ln2_g = (const float*)d_in[11];
    const float* ln2_b = (const float*)d_in[12];
    const float* lnf_g = (const float*)d_in[13];
    const float* lnf_b = (const float*)d_in[14];
    const float* W1    = (const float*)d_in[15];
    const float* b1    = (const float*)d_in[16];
    const float* W2    = (const float*)d_in[17];
    const float* b2    = (const float*)d_in[18];

    char* ws = (char*)d_ws;
    const size_t MB = 1024 * 1024;
    __bf16* Wqt = (__bf16*)(ws + 0 * MB);
    __bf16* Wkt = (__bf16*)(ws + 2 * MB);
    __bf16* Wvt = (__bf16*)(ws + 4 * MB);
    __bf16* Wot = (__bf16*)(ws + 6 * MB);
    __bf16* W1t = (__bf16*)(ws + 8 * MB);    // [FF, E]
    __bf16* W2t = (__bf16*)(ws + 16 * MB);   // [E, FF]
    __bf16* q_bf = (__bf16*)(ws + 24 * MB);
    __bf16* k_bf = (__bf16*)(ws + 40 * MB);
    __bf16* v_bf = (__bf16*)(ws + 56 * MB);
    __bf16* QKb  = (__bf16*)(ws + 72 * MB);  // [M, 2E]
    __bf16* Vtg  = (__bf16*)(ws + 104 * MB); // V^T [E, M]
    __bf16* attn = q_bf;
    __bf16* x_ln = k_bf;
    __bf16* h1   = v_bf;                     // [M, FF] 64MB
    float*  qln  = (float*)(ws + 120 * MB);
    float*  x32  = (float*)(ws + 152 * MB);

    transpose_all<<<12288, 256, 0, stream>>>(Wq, Wk, Wv, Wo, W1, W2,
                                             Wqt, Wkt, Wvt, Wot, W1t, W2t);

    ln3_kernel<<<dim3(M, 3), 256, 0, stream>>>(query, key, value,
                                               ln1_g, ln1_b, ln2_g, ln2_b,
                                               qln, q_bf, k_bf, v_bf);

    // merged Q|K projection -> QKb [M, 2E]; Q side scaled (1/8)*log2(e).
    gemm128<0><<<16 * 64, 256, 0, stream>>>(
        q_bf, k_bf, Wqt, Wkt, nullptr, nullptr, QKb, M, 2 * E, E, E,
        0.125f * 1.44269504088896f);

    // V projection -> V^T [E, M]. grid 8*64.
    gemmV<<<8 * 64, 256, 0, stream>>>(v_bf, Wvt, Vtg, M, E, E);

    attn_kernel<<<dim3(S / 256, Bb * 16), 512, 0, stream>>>(QKb, Vtg, mask, attn);

    // out proj + bias + residual(qln) -> x32 (f32). grid 8*64.
    gemm128<1><<<8 * 64, 256, 0, stream>>>(
        attn, attn, Wot, Wot, bo, qln, x32, M, E, E, E, 1.0f);

    ln_kernel<<<M, 256, 0, stream>>>(x32, lnf_g, lnf_b, x_ln);

    // FFN1: grid 32*64.
    gemm128<2><<<32 * 64, 256, 0, stream>>>(
        x_ln, x_ln, W1t, W1t, b1, nullptr, h1, M, FF, E, FF, 1.0f);
    // FFN2: grid 8*64.
    gemm128<1><<<8 * 64, 256, 0, stream>>>(
        h1, h1, W2t, W2t, b2, x32, (float*)d_out, M, E, FF, E, 1.0f);
}

// Round 6
// 623.947 us; speedup vs baseline: 1.1039x; 1.0464x over previous
//
#include <hip/hip_runtime.h>
#include <hip/hip_bf16.h>
#include <math.h>

typedef __bf16 bf16x8 __attribute__((ext_vector_type(8)));
typedef __bf16 bf16x4 __attribute__((ext_vector_type(4)));
typedef float f32x4 __attribute__((ext_vector_type(4)));
typedef float f32x2 __attribute__((ext_vector_type(2)));
typedef short s16x4 __attribute__((ext_vector_type(4)));

#define AS1 __attribute__((address_space(1)))
#define AS3 __attribute__((address_space(3)))

__device__ __forceinline__ void gll16(const __bf16* g, __bf16* l) {
    __builtin_amdgcn_global_load_lds((const AS1 unsigned int*)g,
                                     (AS3 unsigned int*)l, 16, 0, 0);
}

#if __has_builtin(__builtin_amdgcn_exp2f)
#define EXP2(x) __builtin_amdgcn_exp2f(x)
#else
#define EXP2(x) __expf((x) * 0.69314718055994530942f)
#endif

// PV matmul with K=16 MFMA: B-operand layout (lane holds B[k=quad*4+j][q=l15])
// matches the QK^T score output layout exactly -> no cross-lane shuffle.
__device__ __forceinline__ f32x4 mfma16x16(bf16x4 a, bf16x4 b, f32x4 c) {
#if __has_builtin(__builtin_amdgcn_mfma_f32_16x16x16bf16_1k)
    union { bf16x4 h; s16x4 s; } ua, ub;
    ua.h = a; ub.h = b;
    return __builtin_amdgcn_mfma_f32_16x16x16bf16_1k(ua.s, ub.s, c, 0, 0, 0);
#else
    f32x4 d = c;
    asm volatile("v_mfma_f32_16x16x16_bf16 %0, %1, %2, %0"
                 : "+v"(d) : "v"(a), "v"(b));
    return d;
#endif
}

// ---------------------------------------------------------------------------
// All 6 weight transposes (fp32 [K,N] -> bf16 [N,K]) in one launch.
// ---------------------------------------------------------------------------
__global__ __launch_bounds__(256) void transpose_all(
    const float* __restrict__ Wq, const float* __restrict__ Wk,
    const float* __restrict__ Wv, const float* __restrict__ Wo,
    const float* __restrict__ W1, const float* __restrict__ W2,
    __bf16* __restrict__ Wqt, __bf16* __restrict__ Wkt,
    __bf16* __restrict__ Wvt, __bf16* __restrict__ Wot,
    __bf16* __restrict__ W1t, __bf16* __restrict__ W2t) {
    int g = blockIdx.x;
    const float* W; __bf16* Wt; int K, N, kt, nt;
    if (g < 4096) {
        int mi = g >> 10, loc = g & 1023;
        K = 1024; N = 1024; kt = loc >> 5; nt = loc & 31;
        W  = mi == 0 ? Wq  : mi == 1 ? Wk  : mi == 2 ? Wv  : Wo;
        Wt = mi == 0 ? Wqt : mi == 1 ? Wkt : mi == 2 ? Wvt : Wot;
    } else if (g < 8192) {
        int loc = g - 4096; W = W1; Wt = W1t;
        K = 1024; N = 4096; kt = loc >> 7; nt = loc & 127;
    } else {
        int loc = g - 8192; W = W2; Wt = W2t;
        K = 4096; N = 1024; kt = loc >> 5; nt = loc & 31;
    }
    int k0 = kt * 32, n0 = nt * 32;
    __shared__ float tile[32][33];
    int tx = threadIdx.x & 31, ty = threadIdx.x >> 5;
    #pragma unroll
    for (int j = ty; j < 32; j += 8)
        tile[j][tx] = W[(size_t)(k0 + j) * N + n0 + tx];
    __syncthreads();
    #pragma unroll
    for (int j = ty; j < 32; j += 8)
        Wt[(size_t)(n0 + j) * K + k0 + tx] = (__bf16)tile[tx][j];
}

// ---------------------------------------------------------------------------
// Fused 3-way pre-norm.
// ---------------------------------------------------------------------------
__global__ __launch_bounds__(256) void ln3_kernel(
    const float* __restrict__ q, const float* __restrict__ k,
    const float* __restrict__ v,
    const float* __restrict__ g1, const float* __restrict__ b1,
    const float* __restrict__ g2, const float* __restrict__ b2,
    float* __restrict__ qln, __bf16* __restrict__ qbf,
    __bf16* __restrict__ kbf, __bf16* __restrict__ vbf) {
    const int E = 1024;
    int which = blockIdx.y;
    const float* x = which == 0 ? q : which == 1 ? k : v;
    const float* g = which == 0 ? g1 : g2;
    const float* bb = which == 0 ? b1 : b2;
    float* o32 = which == 0 ? qln : nullptr;
    __bf16* obf = which == 0 ? qbf : which == 1 ? kbf : vbf;

    size_t row = blockIdx.x;
    int t = threadIdx.x;
    float4 val = ((const float4*)(x + row * E))[t];
    float s  = val.x + val.y + val.z + val.w;
    float s2 = val.x * val.x + val.y * val.y + val.z * val.z + val.w * val.w;
    #pragma unroll
    for (int off = 32; off >= 1; off >>= 1) {
        s  += __shfl_down(s, off);
        s2 += __shfl_down(s2, off);
    }
    __shared__ float red[2][4];
    int wid = t >> 6, lane = t & 63;
    if (lane == 0) { red[0][wid] = s; red[1][wid] = s2; }
    __syncthreads();
    if (t == 0) {
        float S1 = red[0][0] + red[0][1] + red[0][2] + red[0][3];
        float S2 = red[1][0] + red[1][1] + red[1][2] + red[1][3];
        float mean = S1 / E;
        float var  = S2 / E - mean * mean;
        red[0][0] = mean;
        red[1][0] = 1.0f / sqrtf(var + 1e-5f);
    }
    __syncthreads();
    float mean = red[0][0], rstd = red[1][0];
    float4 gv = ((const float4*)g)[t];
    float4 bv = ((const float4*)bb)[t];
    float y0 = (val.x - mean) * rstd * gv.x + bv.x;
    float y1 = (val.y - mean) * rstd * gv.y + bv.y;
    float y2 = (val.z - mean) * rstd * gv.z + bv.z;
    float y3 = (val.w - mean) * rstd * gv.w + bv.w;
    if (o32) ((float4*)(o32 + row * E))[t] = make_float4(y0, y1, y2, y3);
    bf16x4 o;
    o[0] = (__bf16)y0; o[1] = (__bf16)y1; o[2] = (__bf16)y2; o[3] = (__bf16)y3;
    ((bf16x4*)(obf + row * E))[t] = o;
}

// single-input LN (final norm), bf16 out
__global__ __launch_bounds__(256) void ln_kernel(const float* __restrict__ x,
                                                 const float* __restrict__ g,
                                                 const float* __restrict__ bb,
                                                 __bf16* __restrict__ outbf) {
    const int E = 1024;
    size_t row = blockIdx.x;
    int t = threadIdx.x;
    float4 v = ((const float4*)(x + row * E))[t];
    float s  = v.x + v.y + v.z + v.w;
    float s2 = v.x * v.x + v.y * v.y + v.z * v.z + v.w * v.w;
    #pragma unroll
    for (int off = 32; off >= 1; off >>= 1) {
        s  += __shfl_down(s, off);
        s2 += __shfl_down(s2, off);
    }
    __shared__ float red[2][4];
    int wid = t >> 6, lane = t & 63;
    if (lane == 0) { red[0][wid] = s; red[1][wid] = s2; }
    __syncthreads();
    if (t == 0) {
        float S1 = red[0][0] + red[0][1] + red[0][2] + red[0][3];
        float S2 = red[1][0] + red[1][1] + red[1][2] + red[1][3];
        float mean = S1 / E;
        float var  = S2 / E - mean * mean;
        red[0][0] = mean;
        red[1][0] = 1.0f / sqrtf(var + 1e-5f);
    }
    __syncthreads();
    float mean = red[0][0], rstd = red[1][0];
    float4 gv = ((const float4*)g)[t];
    float4 bv = ((const float4*)bb)[t];
    bf16x4 o;
    o[0] = (__bf16)((v.x - mean) * rstd * gv.x + bv.x);
    o[1] = (__bf16)((v.y - mean) * rstd * gv.y + bv.y);
    o[2] = (__bf16)((v.z - mean) * rstd * gv.z + bv.z);
    o[3] = (__bf16)((v.w - mean) * rstd * gv.w + bv.w);
    ((bf16x4*)(outbf + row * E))[t] = o;
}

// ---------------------------------------------------------------------------
// GEMM 128x128 tile (2-barrier structure) — kept for N=1024 outputs.
// ---------------------------------------------------------------------------
template <int EPI>
__global__ __launch_bounds__(256) void gemm128(const __bf16* __restrict__ A,
                                               const __bf16* __restrict__ A2,
                                               const __bf16* __restrict__ Bt,
                                               const __bf16* __restrict__ Bt2,
                                               const float* __restrict__ bias,
                                               const float* __restrict__ resid,
                                               void* __restrict__ Cout,
                                               int M, int N, int K,
                                               int splitN, float scale) {
    __shared__ __bf16 As[128 * 64];
    __shared__ __bf16 Bs[128 * 64];
    int tid  = threadIdx.x;
    int lane = tid & 63, wid = tid >> 6;
    int quad = lane >> 4, l15 = lane & 15;
    int waveM = wid >> 1, waveN = wid & 1;

    int GX = N >> 7;
    int id = blockIdx.x;
    int x8 = id & 7, t = id >> 3;
    size_t rowBase = (size_t)((t / GX) * 8 + x8) * 128;
    size_t colBase = (size_t)(t % GX) * 128;

    const __bf16* Ap = A; const __bf16* Bp = Bt;
    size_t colLoc = colBase;
    float sc = scale;
    if ((int)colBase >= splitN) { Ap = A2; Bp = Bt2; colLoc = colBase - splitN; sc = 1.0f; }

    int lrow8  = lane >> 3;
    int lchunk = (lane & 7) ^ lrow8;
    const __bf16* Ag0 = Ap + (rowBase + wid * 32 + lrow8) * (size_t)K + lchunk * 8;
    const __bf16* Bg0 = Bp + (colLoc  + wid * 32 + lrow8) * (size_t)K + lchunk * 8;
    __bf16* AsB = &As[(wid * 32) * 64];
    __bf16* BsB = &Bs[(wid * 32) * 64];

    f32x4 acc[4][4] = {};
    int swz = l15 & 7;

    for (int kb = 0; kb < K; kb += 64) {
        __syncthreads();
        #pragma unroll
        for (int i = 0; i < 4; i++) {
            gll16(Ag0 + (size_t)i * 8 * K + kb, AsB + i * 512);
            gll16(Bg0 + (size_t)i * 8 * K + kb, BsB + i * 512);
        }
        __syncthreads();
        #pragma unroll
        for (int ks = 0; ks < 2; ks++) {
            int p = ((ks * 4 + quad) ^ swz) * 8;
            bf16x8 af[4], bfr[4];
            #pragma unroll
            for (int mi = 0; mi < 4; mi++)
                af[mi] = *(const bf16x8*)&As[(waveM * 64 + mi * 16 + l15) * 64 + p];
            #pragma unroll
            for (int ni = 0; ni < 4; ni++)
                bfr[ni] = *(const bf16x8*)&Bs[(waveN * 64 + ni * 16 + l15) * 64 + p];
            #pragma unroll
            for (int mi = 0; mi < 4; mi++)
                #pragma unroll
                for (int ni = 0; ni < 4; ni++)
                    acc[mi][ni] = __builtin_amdgcn_mfma_f32_16x16x32_bf16(
                        bfr[ni], af[mi], acc[mi][ni], 0, 0, 0);  // swapped: C^T
        }
    }

    #pragma unroll
    for (int mi = 0; mi < 4; mi++)
    #pragma unroll
    for (int ni = 0; ni < 4; ni++) {
        size_t row = rowBase + waveM * 64 + mi * 16 + l15;
        size_t col = colBase + waveN * 64 + ni * 16 + quad * 4;
        f32x4 v = acc[mi][ni];
        if (EPI == 1) {
            float4 b4 = *(const float4*)&bias[col];
            float4 r4 = *(const float4*)&resid[row * N + col];
            float4 o;
            o.x = v[0] + b4.x + r4.x; o.y = v[1] + b4.y + r4.y;
            o.z = v[2] + b4.z + r4.z; o.w = v[3] + b4.w + r4.w;
            *(float4*)&((float*)Cout)[row * N + col] = o;
        } else if (EPI == 2) {
            float4 b4 = *(const float4*)&bias[col];
            bf16x4 pk;
            #pragma unroll
            for (int r = 0; r < 4; r++) {
                float t2 = v[r] + ((const float*)&b4)[r];
                pk[r] = (__bf16)(0.5f * t2 * (1.0f + erff(t2 * 0.70710678118654752f)));
            }
            *(bf16x4*)&((__bf16*)Cout)[row * N + col] = pk;
        } else {
            bf16x4 pk;
            #pragma unroll
            for (int r = 0; r < 4; r++) pk[r] = (__bf16)(v[r] * sc);
            *(bf16x4*)&((__bf16*)Cout)[row * N + col] = pk;
        }
    }
}

// ---------------------------------------------------------------------------
// GEMM 256x256 tile, BK=64, 8 waves (2Mx4N), double-buffered LDS (128KB),
// 4-phase-per-K-tile schedule (T3/T4/T5): staging for tile t+1 is issued in
// phases 0-1 of tile t and drains under ~3 phases of MFMA; raw s_barriers
// cluster the MFMA windows (scheduling only — every cross-buffer hazard is
// gated by the single __syncthreads at the tile boundary). setprio around
// MFMA clusters. Per-wave output 128x64 (acc[8][4]).
// ---------------------------------------------------------------------------
template <int EPI>
__global__ __launch_bounds__(512, 2) void gemm256(const __bf16* __restrict__ A,
                                                  const __bf16* __restrict__ A2,
                                                  const __bf16* __restrict__ Bt,
                                                  const __bf16* __restrict__ Bt2,
                                                  const float* __restrict__ bias,
                                                  const float* __restrict__ resid,
                                                  void* __restrict__ Cout,
                                                  int M, int N, int K,
                                                  int splitN, float scale) {
    __shared__ __bf16 As[2][256 * 64];
    __shared__ __bf16 Bs[2][256 * 64];
    int tid  = threadIdx.x;
    int lane = tid & 63, wid = tid >> 6;          // 8 waves
    int quad = lane >> 4, l15 = lane & 15;
    int waveM = wid >> 2, waveN = wid & 3;        // 2 x 4

    int GX = N >> 8;
    int id = blockIdx.x;
    int x8 = id & 7, tt = id >> 3;
    size_t rowBase = (size_t)((tt / GX) * 8 + x8) * 256;
    size_t colBase = (size_t)(tt % GX) * 256;

    const __bf16* Ap = A; const __bf16* Bp = Bt;
    size_t colLoc = colBase;
    float sc = scale;
    if ((int)colBase >= splitN) { Ap = A2; Bp = Bt2; colLoc = colBase - splitN; sc = 1.0f; }

    int lrow8  = lane >> 3;
    int lchunk = (lane & 7) ^ lrow8;              // inverse-swizzled source
    const __bf16* Ag0 = Ap + (rowBase + wid * 32 + lrow8) * (size_t)K + lchunk * 8;
    const __bf16* Bg0 = Bp + (colLoc  + wid * 32 + lrow8) * (size_t)K + lchunk * 8;
    int ldsB = (wid * 32) * 64;                   // wave's staging base (elems)

    f32x4 acc[8][4] = {};
    int swz = l15 & 7;
    int nsteps = K >> 6;

    // prologue: stage tile 0 into buf 0
    #pragma unroll
    for (int i = 0; i < 4; i++) {
        gll16(Ag0 + (size_t)i * 8 * K, &As[0][ldsB + i * 512]);
        gll16(Bg0 + (size_t)i * 8 * K, &Bs[0][ldsB + i * 512]);
    }
    __syncthreads();

    for (int t = 0; t < nsteps; t++) {
        int cur = t & 1;
        const __bf16* Asb = &As[cur][0];
        const __bf16* Bsb = &Bs[cur][0];
        __bf16* Asn = &As[cur ^ 1][0];
        __bf16* Bsn = &Bs[cur ^ 1][0];
        bool pre = (t + 1 < nsteps);
        size_t kb = (size_t)(t + 1) << 6;

        bf16x8 af[4], bfr[4];
        int p0 = (quad ^ swz) * 8;
        int p1 = ((4 + quad) ^ swz) * 8;

        // ---- phase 0: read B(ks0) + A(ks0,mi0-3); stage next-A; MFMA ----
        #pragma unroll
        for (int ni = 0; ni < 4; ni++)
            bfr[ni] = *(const bf16x8*)&Bsb[(waveN * 64 + ni * 16 + l15) * 64 + p0];
        #pragma unroll
        for (int mi = 0; mi < 4; mi++)
            af[mi] = *(const bf16x8*)&Asb[(waveM * 128 + mi * 16 + l15) * 64 + p0];
        if (pre) {
            #pragma unroll
            for (int i = 0; i < 4; i++)
                gll16(Ag0 + (size_t)i * 8 * K + kb, &Asn[ldsB + i * 512]);
        }
        __builtin_amdgcn_s_barrier();
        __builtin_amdgcn_s_setprio(1);
        #pragma unroll
        for (int mi = 0; mi < 4; mi++)
            #pragma unroll
            for (int ni = 0; ni < 4; ni++)
                acc[mi][ni] = __builtin_amdgcn_mfma_f32_16x16x32_bf16(
                    bfr[ni], af[mi], acc[mi][ni], 0, 0, 0);
        __builtin_amdgcn_s_setprio(0);
        __builtin_amdgcn_s_barrier();

        // ---- phase 1: read A(ks0,mi4-7); stage next-B; MFMA (reuses bfr) --
        #pragma unroll
        for (int mi = 0; mi < 4; mi++)
            af[mi] = *(const bf16x8*)&Asb[(waveM * 128 + (mi + 4) * 16 + l15) * 64 + p0];
        if (pre) {
            #pragma unroll
            for (int i = 0; i < 4; i++)
                gll16(Bg0 + (size_t)i * 8 * K + kb, &Bsn[ldsB + i * 512]);
        }
        __builtin_amdgcn_s_barrier();
        __builtin_amdgcn_s_setprio(1);
        #pragma unroll
        for (int mi = 0; mi < 4; mi++)
            #pragma unroll
            for (int ni = 0; ni < 4; ni++)
                acc[mi + 4][ni] = __builtin_amdgcn_mfma_f32_16x16x32_bf16(
                    bfr[ni], af[mi], acc[mi + 4][ni], 0, 0, 0);
        __builtin_amdgcn_s_setprio(0);
        __builtin_amdgcn_s_barrier();

        // ---- phase 2: read B(ks1) + A(ks1,mi0-3); MFMA ----
        #pragma unroll
        for (int ni = 0; ni < 4; ni++)
            bfr[ni] = *(const bf16x8*)&Bsb[(waveN * 64 + ni * 16 + l15) * 64 + p1];
        #pragma unroll
        for (int mi = 0; mi < 4; mi++)
            af[mi] = *(const bf16x8*)&Asb[(waveM * 128 + mi * 16 + l15) * 64 + p1];
        __builtin_amdgcn_s_barrier();
        __builtin_amdgcn_s_setprio(1);
        #pragma unroll
        for (int mi = 0; mi < 4; mi++)
            #pragma unroll
            for (int ni = 0; ni < 4; ni++)
                acc[mi][ni] = __builtin_amdgcn_mfma_f32_16x16x32_bf16(
                    bfr[ni], af[mi], acc[mi][ni], 0, 0, 0);
        __builtin_amdgcn_s_setprio(0);
        __builtin_amdgcn_s_barrier();

        // ---- phase 3: read A(ks1,mi4-7); MFMA; tile-boundary full sync ----
        #pragma unroll
        for (int mi = 0; mi < 4; mi++)
            af[mi] = *(const bf16x8*)&Asb[(waveM * 128 + (mi + 4) * 16 + l15) * 64 + p1];
        __builtin_amdgcn_s_setprio(1);
        #pragma unroll
        for (int mi = 0; mi < 4; mi++)
            #pragma unroll
            for (int ni = 0; ni < 4; ni++)
                acc[mi + 4][ni] = __builtin_amdgcn_mfma_f32_16x16x32_bf16(
                    bfr[ni], af[mi], acc[mi + 4][ni], 0, 0, 0);
        __builtin_amdgcn_s_setprio(0);
        __syncthreads();   // drains vmcnt (staging) + lgkm; gates buffer swap
    }

    #pragma unroll
    for (int mi = 0; mi < 8; mi++)
    #pragma unroll
    for (int ni = 0; ni < 4; ni++) {
        size_t row = rowBase + waveM * 128 + mi * 16 + l15;
        size_t col = colBase + waveN * 64 + ni * 16 + quad * 4;
        f32x4 v = acc[mi][ni];
        if (EPI == 1) {
            float4 b4 = *(const float4*)&bias[col];
            float4 r4 = *(const float4*)&resid[row * N + col];
            float4 o;
            o.x = v[0] + b4.x + r4.x; o.y = v[1] + b4.y + r4.y;
            o.z = v[2] + b4.z + r4.z; o.w = v[3] + b4.w + r4.w;
            *(float4*)&((float*)Cout)[row * N + col] = o;
        } else if (EPI == 2) {
            float4 b4 = *(const float4*)&bias[col];
            bf16x4 pk;
            #pragma unroll
            for (int r = 0; r < 4; r++) {
                float t2 = v[r] + ((const float*)&b4)[r];
                pk[r] = (__bf16)(0.5f * t2 * (1.0f + erff(t2 * 0.70710678118654752f)));
            }
            *(bf16x4*)&((__bf16*)Cout)[row * N + col] = pk;
        } else {
            bf16x4 pk;
            #pragma unroll
            for (int r = 0; r < 4; r++) pk[r] = (__bf16)(v[r] * sc);
            *(bf16x4*)&((__bf16*)Cout)[row * N + col] = pk;
        }
    }
}

// ---------------------------------------------------------------------------
// V projection GEMM (non-swapped MFMA) writing V^T [E, M], packed stores.
// ---------------------------------------------------------------------------
__global__ __launch_bounds__(256) void gemmV(const __bf16* __restrict__ A,
                                             const __bf16* __restrict__ Bt,
                                             __bf16* __restrict__ Cout,
                                             int M, int N, int K) {
    __shared__ __bf16 As[128 * 64];
    __shared__ __bf16 Bs[128 * 64];
    int tid  = threadIdx.x;
    int lane = tid & 63, wid = tid >> 6;
    int quad = lane >> 4, l15 = lane & 15;
    int waveM = wid >> 1, waveN = wid & 1;

    int GX = N >> 7;
    int id = blockIdx.x;
    int x8 = id & 7, t = id >> 3;
    size_t rowBase = (size_t)((t / GX) * 8 + x8) * 128;
    size_t colBase = (size_t)(t % GX) * 128;

    int lrow8  = lane >> 3;
    int lchunk = (lane & 7) ^ lrow8;
    const __bf16* Ag0 = A  + (rowBase + wid * 32 + lrow8) * (size_t)K + lchunk * 8;
    const __bf16* Bg0 = Bt + (colBase + wid * 32 + lrow8) * (size_t)K + lchunk * 8;
    __bf16* AsB = &As[(wid * 32) * 64];
    __bf16* BsB = &Bs[(wid * 32) * 64];

    f32x4 acc[4][4] = {};
    int swz = l15 & 7;

    for (int kb = 0; kb < K; kb += 64) {
        __syncthreads();
        #pragma unroll
        for (int i = 0; i < 4; i++) {
            gll16(Ag0 + (size_t)i * 8 * K + kb, AsB + i * 512);
            gll16(Bg0 + (size_t)i * 8 * K + kb, BsB + i * 512);
        }
        __syncthreads();
        #pragma unroll
        for (int ks = 0; ks < 2; ks++) {
            int p = ((ks * 4 + quad) ^ swz) * 8;
            bf16x8 af[4], bfr[4];
            #pragma unroll
            for (int mi = 0; mi < 4; mi++)
                af[mi] = *(const bf16x8*)&As[(waveM * 64 + mi * 16 + l15) * 64 + p];
            #pragma unroll
            for (int ni = 0; ni < 4; ni++)
                bfr[ni] = *(const bf16x8*)&Bs[(waveN * 64 + ni * 16 + l15) * 64 + p];
            #pragma unroll
            for (int mi = 0; mi < 4; mi++)
                #pragma unroll
                for (int ni = 0; ni < 4; ni++)
                    acc[mi][ni] = __builtin_amdgcn_mfma_f32_16x16x32_bf16(
                        af[mi], bfr[ni], acc[mi][ni], 0, 0, 0);
        }
    }

    #pragma unroll
    for (int mi = 0; mi < 4; mi++)
    #pragma unroll
    for (int ni = 0; ni < 4; ni++) {
        size_t col = colBase + waveN * 64 + ni * 16 + l15;        // dim in E
        size_t m0  = rowBase + waveM * 64 + mi * 16 + quad * 4;   // token
        bf16x4 pk;
        #pragma unroll
        for (int r = 0; r < 4; r++) pk[r] = (__bf16)acc[mi][ni][r];
        *(bf16x4*)&Cout[col * M + m0] = pk;
    }
}

// ---------------------------------------------------------------------------
// Flash attention, transposed-score formulation, 512 threads (8 waves).
// Each wave owns 32 q-rows (2 groups of 16). PV uses 16x16x16 MFMA.
// ---------------------------------------------------------------------------
__global__ __launch_bounds__(512, 4) void attn_kernel(const __bf16* __restrict__ QK,
                                                      const __bf16* __restrict__ Vt,
                                                      const int* __restrict__ mask,
                                                      __bf16* __restrict__ Out) {
    const int S = 2048, E = 1024, E2 = 2048, M = 8192;
    int qt = blockIdx.x, bh = blockIdx.y;
    int b = bh >> 4, h = bh & 15;
    int q0 = qt * 256;
    int tid = threadIdx.x, lane = tid & 63, wid = tid >> 6;  // wid 0..7
    int quad = lane >> 4, l15 = lane & 15;

    __shared__ __bf16 Ks[2][4096];
    __shared__ __bf16 Vs[2][4096];

    bf16x8 aq[2][2];
    #pragma unroll
    for (int g = 0; g < 2; g++)
    #pragma unroll
    for (int hh = 0; hh < 2; hh++) {
        size_t row = (size_t)(b * S + q0 + wid * 32 + g * 16 + l15);
        aq[g][hh] = *(const bf16x8*)(QK + row * E2 + h * 64 + hh * 32 + quad * 8);
    }

    int lrow8  = lane >> 3;
    int lchunk = (lane & 7) ^ lrow8;
    const __bf16* Kg0 = QK + (size_t)(b * S + wid * 8 + lrow8) * E2 + 1024 + h * 64 + lchunk * 8;

    // V reg-staging: thread (rv, cv) loads global 16B chunk cv of V^T row rv.
    int rv = tid >> 3, cv = tid & 7;
    const __bf16* Vg0 = Vt + (size_t)(h * 64 + rv) * M + b * S + cv * 8;
    int c0   = ((cv & 1) << 2) + (cv >> 2);
    int lowb = (cv >> 1) & 1;
    int sv   = rv & 7;
    int wo0  = rv * 64 + ((c0 ^ sv) << 3) + (lowb << 2);
    int wo1  = rv * 64 + (((c0 + 2) ^ sv) << 3) + (lowb << 2);

    int swz = l15 & 7;

    f32x4 accO[2][4] = {};
    f32x2 acc2[2] = {};

    bf16x8 vreg = *(const bf16x8*)(Vg0);
    gll16(Kg0, &Ks[0][wid * 512]);
    *(bf16x4*)&Vs[0][wo0] = __builtin_shufflevector(vreg, vreg, 0, 1, 2, 3);
    *(bf16x4*)&Vs[0][wo1] = __builtin_shufflevector(vreg, vreg, 4, 5, 6, 7);
    __syncthreads();

    for (int kt = 0; kt < S / 64; kt++) {
        int k0 = kt * 64;
        int buf = kt & 1;
        if (kt + 1 < S / 64) {
            vreg = *(const bf16x8*)(Vg0 + k0 + 64);            // issue early (T14)
            gll16(Kg0 + (size_t)(k0 + 64) * E2, &Ks[buf ^ 1][wid * 512]);
        }
        const __bf16* Ksb = &Ks[buf][0];
        const __bf16* Vsb = &Vs[buf][0];

        bf16x4 pb[2][4];
        #pragma unroll
        for (int nt = 0; nt < 4; nt++) {
            bf16x8 a0 = *(const bf16x8*)&Ksb[(nt * 16 + l15) * 64 + ((quad) ^ swz) * 8];
            bf16x8 a1 = *(const bf16x8*)&Ksb[(nt * 16 + l15) * 64 + ((4 + quad) ^ swz) * 8];
            int4 mz = *(const int4*)&mask[b * S + k0 + nt * 16 + quad * 4];
            #pragma unroll
            for (int g = 0; g < 2; g++) {
                f32x4 a = {};
                a = __builtin_amdgcn_mfma_f32_16x16x32_bf16(a0, aq[g][0], a, 0, 0, 0);
                a = __builtin_amdgcn_mfma_f32_16x16x32_bf16(a1, aq[g][1], a, 0, 0, 0);
                float p0 = mz.x ? EXP2(a[0]) : 0.f;
                float p1 = mz.y ? EXP2(a[1]) : 0.f;
                float p2 = mz.z ? EXP2(a[2]) : 0.f;
                float p3 = mz.w ? EXP2(a[3]) : 0.f;
                f32x2 t01; t01[0] = p0; t01[1] = p1;
                f32x2 t23; t23[0] = p2; t23[1] = p3;
                acc2[g] += t01 + t23;
                bf16x4 pk;
                pk[0] = (__bf16)p0; pk[1] = (__bf16)p1;
                pk[2] = (__bf16)p2; pk[3] = (__bf16)p3;
                pb[g][nt] = pk;
            }
        }

        // PV: 2x b128 per dt; halves are nt fragments, shared by both groups.
        #pragma unroll
        for (int dt = 0; dt < 4; dt++) {
            const __bf16* vrow = &Vsb[(dt * 16 + l15) * 64];
            bf16x8 vv0 = *(const bf16x8*)&vrow[((quad * 2 + 0) ^ swz) * 8];
            bf16x8 vv1 = *(const bf16x8*)&vrow[((quad * 2 + 1) ^ swz) * 8];
            bf16x4 h00 = __builtin_shufflevector(vv0, vv0, 0, 1, 2, 3);
            bf16x4 h01 = __builtin_shufflevector(vv0, vv0, 4, 5, 6, 7);
            bf16x4 h10 = __builtin_shufflevector(vv1, vv1, 0, 1, 2, 3);
            bf16x4 h11 = __builtin_shufflevector(vv1, vv1, 4, 5, 6, 7);
            #pragma unroll
            for (int g = 0; g < 2; g++) {
                accO[g][dt] = mfma16x16(h00, pb[g][0], accO[g][dt]);
                accO[g][dt] = mfma16x16(h01, pb[g][1], accO[g][dt]);
                accO[g][dt] = mfma16x16(h10, pb[g][2], accO[g][dt]);
                accO[g][dt] = mfma16x16(h11, pb[g][3], accO[g][dt]);
            }
        }

        if (kt + 1 < S / 64) {
            // write-late half of the async stage (vmcnt wait lands here)
            *(bf16x4*)&Vs[buf ^ 1][wo0] = __builtin_shufflevector(vreg, vreg, 0, 1, 2, 3);
            *(bf16x4*)&Vs[buf ^ 1][wo1] = __builtin_shufflevector(vreg, vreg, 4, 5, 6, 7);
        }
        __syncthreads();
    }

    #pragma unroll
    for (int g = 0; g < 2; g++) {
        float l = acc2[g][0] + acc2[g][1];
        l += __shfl_xor(l, 16, 64);
        l += __shfl_xor(l, 32, 64);
        float inv = 1.0f / l;
        #pragma unroll
        for (int dt = 0; dt < 4; dt++) {
            size_t row = (size_t)(b * S + q0 + wid * 32 + g * 16 + l15);
            bf16x4 pk;
            #pragma unroll
            for (int r = 0; r < 4; r++) pk[r] = (__bf16)(accO[g][dt][r] * inv);
            *(bf16x4*)&Out[row * E + h * 64 + dt * 16 + quad * 4] = pk;
        }
    }
}

// ---------------------------------------------------------------------------
// Launch
// ---------------------------------------------------------------------------
extern "C" void kernel_launch(void* const* d_in, const int* in_sizes, int n_in,
                              void* d_out, int out_size, void* d_ws, size_t ws_size,
                              hipStream_t stream) {
    const int Bb = 4, S = 2048, E = 1024, FF = 4096;
    const int M = Bb * S;  // 8192

    const float* value = (const float*)d_in[0];
    const float* key   = (const float*)d_in[1];
    const float* query = (const float*)d_in[2];
    const int*   mask  = (const int*)d_in[3];
    const float* Wv    = (const float*)d_in[4];
    const float* Wk    = (const float*)d_in[5];
    const float* Wq    = (const float*)d_in[6];
    const float* Wo    = (const float*)d_in[7];
    const float* bo    = (const float*)d_in[8];
    const float* ln1_g = (const float*)d_in[9];
    const float* ln1_b = (const float*)d_in[10];
    const float* ln2_g = (const float*)d_in[11];
    const float* ln2_b = (const float*)d_in[12];
    const float* lnf_g = (const float*)d_in[13];
    const float* lnf_b = (const float*)d_in[14];
    const float* W1    = (const float*)d_in[15];
    const float* b1    = (const float*)d_in[16];
    const float* W2    = (const float*)d_in[17];
    const float* b2    = (const float*)d_in[18];

    char* ws = (char*)d_ws;
    const size_t MB = 1024 * 1024;
    __bf16* Wqt = (__bf16*)(ws + 0 * MB);
    __bf16* Wkt = (__bf16*)(ws + 2 * MB);
    __bf16* Wvt = (__bf16*)(ws + 4 * MB);
    __bf16* Wot = (__bf16*)(ws + 6 * MB);
    __bf16* W1t = (__bf16*)(ws + 8 * MB);    // [FF, E]
    __bf16* W2t = (__bf16*)(ws + 16 * MB);   // [E, FF]
    __bf16* q_bf = (__bf16*)(ws + 24 * MB);
    __bf16* k_bf = (__bf16*)(ws + 40 * MB);
    __bf16* v_bf = (__bf16*)(ws + 56 * MB);
    __bf16* QKb  = (__bf16*)(ws + 72 * MB);  // [M, 2E]
    __bf16* Vtg  = (__bf16*)(ws + 104 * MB); // V^T [E, M]
    __bf16* attn = q_bf;
    __bf16* x_ln = k_bf;
    __bf16* h1   = v_bf;                     // [M, FF] 64MB
    float*  qln  = (float*)(ws + 120 * MB);
    float*  x32  = (float*)(ws + 152 * MB);

    transpose_all<<<12288, 256, 0, stream>>>(Wq, Wk, Wv, Wo, W1, W2,
                                             Wqt, Wkt, Wvt, Wot, W1t, W2t);

    ln3_kernel<<<dim3(M, 3), 256, 0, stream>>>(query, key, value,
                                               ln1_g, ln1_b, ln2_g, ln2_b,
                                               qln, q_bf, k_bf, v_bf);

    // merged Q|K projection -> QKb [M, 2E]; Q side scaled (1/8)*log2(e).
    // 256² 8-phase: grid (8192/256)*(2048/256) = 32*8 = 256.
    gemm256<0><<<256, 512, 0, stream>>>(
        q_bf, k_bf, Wqt, Wkt, nullptr, nullptr, QKb, M, 2 * E, E, E,
        0.125f * 1.44269504088896f);

    // V projection -> V^T [E, M]. grid 8*64 (128² kept: N=1024).
    gemmV<<<8 * 64, 256, 0, stream>>>(v_bf, Wvt, Vtg, M, E, E);

    attn_kernel<<<dim3(S / 256, Bb * 16), 512, 0, stream>>>(QKb, Vtg, mask, attn);

    // out proj + bias + residual(qln) -> x32 (f32). 128² kept: N=1024.
    gemm128<1><<<8 * 64, 256, 0, stream>>>(
        attn, attn, Wot, Wot, bo, qln, x32, M, E, E, E, 1.0f);

    ln_kernel<<<M, 256, 0, stream>>>(x32, lnf_g, lnf_b, x_ln);

    // FFN1: 256² 8-phase: grid (8192/256)*(4096/256) = 32*16 = 512.
    gemm256<2><<<512, 512, 0, stream>>>(
        x_ln, x_ln, W1t, W1t, b1, nullptr, h1, M, FF, E, FF, 1.0f);
    // FFN2: 128² kept: N=1024. grid 8*64.
    gemm128<1><<<8 * 64, 256, 0, stream>>>(
        h1, h1, W2t, W2t, b2, x32, (float*)d_out, M, E, FF, E, 1.0f);
}

// Round 8
// 620.681 us; speedup vs baseline: 1.1097x; 1.0053x over previous
//
#include <hip/hip_runtime.h>
#include <hip/hip_bf16.h>
#include <math.h>

typedef __bf16 bf16x8 __attribute__((ext_vector_type(8)));
typedef __bf16 bf16x4 __attribute__((ext_vector_type(4)));
typedef float f32x4 __attribute__((ext_vector_type(4)));
typedef float f32x2 __attribute__((ext_vector_type(2)));
typedef short s16x4 __attribute__((ext_vector_type(4)));

#define AS1 __attribute__((address_space(1)))
#define AS3 __attribute__((address_space(3)))

__device__ __forceinline__ void gll16(const __bf16* g, __bf16* l) {
    __builtin_amdgcn_global_load_lds((const AS1 unsigned int*)g,
                                     (AS3 unsigned int*)l, 16, 0, 0);
}

#if __has_builtin(__builtin_amdgcn_exp2f)
#define EXP2(x) __builtin_amdgcn_exp2f(x)
#else
#define EXP2(x) __expf((x) * 0.69314718055994530942f)
#endif

// PV matmul with K=16 MFMA: B-operand layout (lane holds B[k=quad*4+j][q=l15])
// matches the QK^T score output layout exactly -> no cross-lane shuffle.
__device__ __forceinline__ f32x4 mfma16x16(bf16x4 a, bf16x4 b, f32x4 c) {
#if __has_builtin(__builtin_amdgcn_mfma_f32_16x16x16bf16_1k)
    union { bf16x4 h; s16x4 s; } ua, ub;
    ua.h = a; ub.h = b;
    return __builtin_amdgcn_mfma_f32_16x16x16bf16_1k(ua.s, ub.s, c, 0, 0, 0);
#else
    f32x4 d = c;
    asm volatile("v_mfma_f32_16x16x16_bf16 %0, %1, %2, %0"
                 : "+v"(d) : "v"(a), "v"(b));
    return d;
#endif
}

// ---------------------------------------------------------------------------
// All 6 weight transposes (fp32 [K,N] -> bf16 [N,K]) in one launch.
// ---------------------------------------------------------------------------
__global__ __launch_bounds__(256) void transpose_all(
    const float* __restrict__ Wq, const float* __restrict__ Wk,
    const float* __restrict__ Wv, const float* __restrict__ Wo,
    const float* __restrict__ W1, const float* __restrict__ W2,
    __bf16* __restrict__ Wqt, __bf16* __restrict__ Wkt,
    __bf16* __restrict__ Wvt, __bf16* __restrict__ Wot,
    __bf16* __restrict__ W1t, __bf16* __restrict__ W2t) {
    int g = blockIdx.x;
    const float* W; __bf16* Wt; int K, N, kt, nt;
    if (g < 4096) {
        int mi = g >> 10, loc = g & 1023;
        K = 1024; N = 1024; kt = loc >> 5; nt = loc & 31;
        W  = mi == 0 ? Wq  : mi == 1 ? Wk  : mi == 2 ? Wv  : Wo;
        Wt = mi == 0 ? Wqt : mi == 1 ? Wkt : mi == 2 ? Wvt : Wot;
    } else if (g < 8192) {
        int loc = g - 4096; W = W1; Wt = W1t;
        K = 1024; N = 4096; kt = loc >> 7; nt = loc & 127;
    } else {
        int loc = g - 8192; W = W2; Wt = W2t;
        K = 4096; N = 1024; kt = loc >> 5; nt = loc & 31;
    }
    int k0 = kt * 32, n0 = nt * 32;
    __shared__ float tile[32][33];
    int tx = threadIdx.x & 31, ty = threadIdx.x >> 5;
    #pragma unroll
    for (int j = ty; j < 32; j += 8)
        tile[j][tx] = W[(size_t)(k0 + j) * N + n0 + tx];
    __syncthreads();
    #pragma unroll
    for (int j = ty; j < 32; j += 8)
        Wt[(size_t)(n0 + j) * K + k0 + tx] = (__bf16)tile[tx][j];
}

// ---------------------------------------------------------------------------
// Fused 3-way pre-norm.
// ---------------------------------------------------------------------------
__global__ __launch_bounds__(256) void ln3_kernel(
    const float* __restrict__ q, const float* __restrict__ k,
    const float* __restrict__ v,
    const float* __restrict__ g1, const float* __restrict__ b1,
    const float* __restrict__ g2, const float* __restrict__ b2,
    float* __restrict__ qln, __bf16* __restrict__ qbf,
    __bf16* __restrict__ kbf, __bf16* __restrict__ vbf) {
    const int E = 1024;
    int which = blockIdx.y;
    const float* x = which == 0 ? q : which == 1 ? k : v;
    const float* g = which == 0 ? g1 : g2;
    const float* bb = which == 0 ? b1 : b2;
    float* o32 = which == 0 ? qln : nullptr;
    __bf16* obf = which == 0 ? qbf : which == 1 ? kbf : vbf;

    size_t row = blockIdx.x;
    int t = threadIdx.x;
    float4 val = ((const float4*)(x + row * E))[t];
    float s  = val.x + val.y + val.z + val.w;
    float s2 = val.x * val.x + val.y * val.y + val.z * val.z + val.w * val.w;
    #pragma unroll
    for (int off = 32; off >= 1; off >>= 1) {
        s  += __shfl_down(s, off);
        s2 += __shfl_down(s2, off);
    }
    __shared__ float red[2][4];
    int wid = t >> 6, lane = t & 63;
    if (lane == 0) { red[0][wid] = s; red[1][wid] = s2; }
    __syncthreads();
    if (t == 0) {
        float S1 = red[0][0] + red[0][1] + red[0][2] + red[0][3];
        float S2 = red[1][0] + red[1][1] + red[1][2] + red[1][3];
        float mean = S1 / E;
        float var  = S2 / E - mean * mean;
        red[0][0] = mean;
        red[1][0] = 1.0f / sqrtf(var + 1e-5f);
    }
    __syncthreads();
    float mean = red[0][0], rstd = red[1][0];
    float4 gv = ((const float4*)g)[t];
    float4 bv = ((const float4*)bb)[t];
    float y0 = (val.x - mean) * rstd * gv.x + bv.x;
    float y1 = (val.y - mean) * rstd * gv.y + bv.y;
    float y2 = (val.z - mean) * rstd * gv.z + bv.z;
    float y3 = (val.w - mean) * rstd * gv.w + bv.w;
    if (o32) ((float4*)(o32 + row * E))[t] = make_float4(y0, y1, y2, y3);
    bf16x4 o;
    o[0] = (__bf16)y0; o[1] = (__bf16)y1; o[2] = (__bf16)y2; o[3] = (__bf16)y3;
    ((bf16x4*)(obf + row * E))[t] = o;
}

// single-input LN (final norm), bf16 out
__global__ __launch_bounds__(256) void ln_kernel(const float* __restrict__ x,
                                                 const float* __restrict__ g,
                                                 const float* __restrict__ bb,
                                                 __bf16* __restrict__ outbf) {
    const int E = 1024;
    size_t row = blockIdx.x;
    int t = threadIdx.x;
    float4 v = ((const float4*)(x + row * E))[t];
    float s  = v.x + v.y + v.z + v.w;
    float s2 = v.x * v.x + v.y * v.y + v.z * v.z + v.w * v.w;
    #pragma unroll
    for (int off = 32; off >= 1; off >>= 1) {
        s  += __shfl_down(s, off);
        s2 += __shfl_down(s2, off);
    }
    __shared__ float red[2][4];
    int wid = t >> 6, lane = t & 63;
    if (lane == 0) { red[0][wid] = s; red[1][wid] = s2; }
    __syncthreads();
    if (t == 0) {
        float S1 = red[0][0] + red[0][1] + red[0][2] + red[0][3];
        float S2 = red[1][0] + red[1][1] + red[1][2] + red[1][3];
        float mean = S1 / E;
        float var  = S2 / E - mean * mean;
        red[0][0] = mean;
        red[1][0] = 1.0f / sqrtf(var + 1e-5f);
    }
    __syncthreads();
    float mean = red[0][0], rstd = red[1][0];
    float4 gv = ((const float4*)g)[t];
    float4 bv = ((const float4*)bb)[t];
    bf16x4 o;
    o[0] = (__bf16)((v.x - mean) * rstd * gv.x + bv.x);
    o[1] = (__bf16)((v.y - mean) * rstd * gv.y + bv.y);
    o[2] = (__bf16)((v.z - mean) * rstd * gv.z + bv.z);
    o[3] = (__bf16)((v.w - mean) * rstd * gv.w + bv.w);
    ((bf16x4*)(outbf + row * E))[t] = o;
}

// ---------------------------------------------------------------------------
// GEMM 128x128 tile (2-barrier structure) — kept for gemmV-size jobs.
// ---------------------------------------------------------------------------
template <int EPI>
__global__ __launch_bounds__(256) void gemm128(const __bf16* __restrict__ A,
                                               const __bf16* __restrict__ A2,
                                               const __bf16* __restrict__ Bt,
                                               const __bf16* __restrict__ Bt2,
                                               const float* __restrict__ bias,
                                               const float* __restrict__ resid,
                                               void* __restrict__ Cout,
                                               int M, int N, int K,
                                               int splitN, float scale) {
    __shared__ __bf16 As[128 * 64];
    __shared__ __bf16 Bs[128 * 64];
    int tid  = threadIdx.x;
    int lane = tid & 63, wid = tid >> 6;
    int quad = lane >> 4, l15 = lane & 15;
    int waveM = wid >> 1, waveN = wid & 1;

    int GX = N >> 7;
    int id = blockIdx.x;
    int x8 = id & 7, t = id >> 3;
    size_t rowBase = (size_t)((t / GX) * 8 + x8) * 128;
    size_t colBase = (size_t)(t % GX) * 128;

    const __bf16* Ap = A; const __bf16* Bp = Bt;
    size_t colLoc = colBase;
    float sc = scale;
    if ((int)colBase >= splitN) { Ap = A2; Bp = Bt2; colLoc = colBase - splitN; sc = 1.0f; }

    int lrow8  = lane >> 3;
    int lchunk = (lane & 7) ^ lrow8;
    const __bf16* Ag0 = Ap + (rowBase + wid * 32 + lrow8) * (size_t)K + lchunk * 8;
    const __bf16* Bg0 = Bp + (colLoc  + wid * 32 + lrow8) * (size_t)K + lchunk * 8;
    __bf16* AsB = &As[(wid * 32) * 64];
    __bf16* BsB = &Bs[(wid * 32) * 64];

    f32x4 acc[4][4] = {};
    int swz = l15 & 7;

    for (int kb = 0; kb < K; kb += 64) {
        __syncthreads();
        #pragma unroll
        for (int i = 0; i < 4; i++) {
            gll16(Ag0 + (size_t)i * 8 * K + kb, AsB + i * 512);
            gll16(Bg0 + (size_t)i * 8 * K + kb, BsB + i * 512);
        }
        __syncthreads();
        #pragma unroll
        for (int ks = 0; ks < 2; ks++) {
            int p = ((ks * 4 + quad) ^ swz) * 8;
            bf16x8 af[4], bfr[4];
            #pragma unroll
            for (int mi = 0; mi < 4; mi++)
                af[mi] = *(const bf16x8*)&As[(waveM * 64 + mi * 16 + l15) * 64 + p];
            #pragma unroll
            for (int ni = 0; ni < 4; ni++)
                bfr[ni] = *(const bf16x8*)&Bs[(waveN * 64 + ni * 16 + l15) * 64 + p];
            #pragma unroll
            for (int mi = 0; mi < 4; mi++)
                #pragma unroll
                for (int ni = 0; ni < 4; ni++)
                    acc[mi][ni] = __builtin_amdgcn_mfma_f32_16x16x32_bf16(
                        bfr[ni], af[mi], acc[mi][ni], 0, 0, 0);  // swapped: C^T
        }
    }

    #pragma unroll
    for (int mi = 0; mi < 4; mi++)
    #pragma unroll
    for (int ni = 0; ni < 4; ni++) {
        size_t row = rowBase + waveM * 64 + mi * 16 + l15;
        size_t col = colBase + waveN * 64 + ni * 16 + quad * 4;
        f32x4 v = acc[mi][ni];
        if (EPI == 1) {
            float4 b4 = *(const float4*)&bias[col];
            float4 r4 = *(const float4*)&resid[row * N + col];
            float4 o;
            o.x = v[0] + b4.x + r4.x; o.y = v[1] + b4.y + r4.y;
            o.z = v[2] + b4.z + r4.z; o.w = v[3] + b4.w + r4.w;
            *(float4*)&((float*)Cout)[row * N + col] = o;
        } else if (EPI == 2) {
            float4 b4 = *(const float4*)&bias[col];
            bf16x4 pk;
            #pragma unroll
            for (int r = 0; r < 4; r++) {
                float t2 = v[r] + ((const float*)&b4)[r];
                pk[r] = (__bf16)(0.5f * t2 * (1.0f + erff(t2 * 0.70710678118654752f)));
            }
            *(bf16x4*)&((__bf16*)Cout)[row * N + col] = pk;
        } else {
            bf16x4 pk;
            #pragma unroll
            for (int r = 0; r < 4; r++) pk[r] = (__bf16)(v[r] * sc);
            *(bf16x4*)&((__bf16*)Cout)[row * N + col] = pk;
        }
    }
}

// ---------------------------------------------------------------------------
// GEMM 256x256 tile, BK=64, 8 waves (2Mx4N), double-buffered LDS (128KB),
// 4-phase-per-K-tile schedule: staging for tile t+1 is issued in phases 0-1
// of tile t and drains under ~3 phases of MFMA. Raw s_barriers are
// scheduling-only; cross-buffer hazards gated by the tile-boundary
// __syncthreads. Per-wave output 128x64 (acc[8][4]).
// ---------------------------------------------------------------------------
template <int EPI>
__global__ __launch_bounds__(512, 2) void gemm256(const __bf16* __restrict__ A,
                                                  const __bf16* __restrict__ A2,
                                                  const __bf16* __restrict__ Bt,
                                                  const __bf16* __restrict__ Bt2,
                                                  const float* __restrict__ bias,
                                                  const float* __restrict__ resid,
                                                  void* __restrict__ Cout,
                                                  int M, int N, int K,
                                                  int splitN, float scale) {
    __shared__ __bf16 As[2][256 * 64];
    __shared__ __bf16 Bs[2][256 * 64];
    int tid  = threadIdx.x;
    int lane = tid & 63, wid = tid >> 6;          // 8 waves
    int quad = lane >> 4, l15 = lane & 15;
    int waveM = wid >> 2, waveN = wid & 3;        // 2 x 4

    int GX = N >> 8;
    int id = blockIdx.x;
    int x8 = id & 7, tt = id >> 3;
    size_t rowBase = (size_t)((tt / GX) * 8 + x8) * 256;
    size_t colBase = (size_t)(tt % GX) * 256;

    const __bf16* Ap = A; const __bf16* Bp = Bt;
    size_t colLoc = colBase;
    float sc = scale;
    if ((int)colBase >= splitN) { Ap = A2; Bp = Bt2; colLoc = colBase - splitN; sc = 1.0f; }

    int lrow8  = lane >> 3;
    int lchunk = (lane & 7) ^ lrow8;              // inverse-swizzled source
    const __bf16* Ag0 = Ap + (rowBase + wid * 32 + lrow8) * (size_t)K + lchunk * 8;
    const __bf16* Bg0 = Bp + (colLoc  + wid * 32 + lrow8) * (size_t)K + lchunk * 8;
    int ldsB = (wid * 32) * 64;                   // wave's staging base (elems)

    f32x4 acc[8][4] = {};
    int swz = l15 & 7;
    int nsteps = K >> 6;

    // prologue: stage tile 0 into buf 0
    #pragma unroll
    for (int i = 0; i < 4; i++) {
        gll16(Ag0 + (size_t)i * 8 * K, &As[0][ldsB + i * 512]);
        gll16(Bg0 + (size_t)i * 8 * K, &Bs[0][ldsB + i * 512]);
    }
    __syncthreads();

    for (int t = 0; t < nsteps; t++) {
        int cur = t & 1;
        const __bf16* Asb = &As[cur][0];
        const __bf16* Bsb = &Bs[cur][0];
        __bf16* Asn = &As[cur ^ 1][0];
        __bf16* Bsn = &Bs[cur ^ 1][0];
        bool pre = (t + 1 < nsteps);
        size_t kb = (size_t)(t + 1) << 6;

        bf16x8 af[4], bfr[4];
        int p0 = (quad ^ swz) * 8;
        int p1 = ((4 + quad) ^ swz) * 8;

        // ---- phase 0: read B(ks0) + A(ks0,mi0-3); stage next-A; MFMA ----
        #pragma unroll
        for (int ni = 0; ni < 4; ni++)
            bfr[ni] = *(const bf16x8*)&Bsb[(waveN * 64 + ni * 16 + l15) * 64 + p0];
        #pragma unroll
        for (int mi = 0; mi < 4; mi++)
            af[mi] = *(const bf16x8*)&Asb[(waveM * 128 + mi * 16 + l15) * 64 + p0];
        if (pre) {
            #pragma unroll
            for (int i = 0; i < 4; i++)
                gll16(Ag0 + (size_t)i * 8 * K + kb, &Asn[ldsB + i * 512]);
        }
        __builtin_amdgcn_s_barrier();
        __builtin_amdgcn_s_setprio(1);
        #pragma unroll
        for (int mi = 0; mi < 4; mi++)
            #pragma unroll
            for (int ni = 0; ni < 4; ni++)
                acc[mi][ni] = __builtin_amdgcn_mfma_f32_16x16x32_bf16(
                    bfr[ni], af[mi], acc[mi][ni], 0, 0, 0);
        __builtin_amdgcn_s_setprio(0);
        __builtin_amdgcn_s_barrier();

        // ---- phase 1: read A(ks0,mi4-7); stage next-B; MFMA (reuses bfr) --
        #pragma unroll
        for (int mi = 0; mi < 4; mi++)
            af[mi] = *(const bf16x8*)&Asb[(waveM * 128 + (mi + 4) * 16 + l15) * 64 + p0];
        if (pre) {
            #pragma unroll
            for (int i = 0; i < 4; i++)
                gll16(Bg0 + (size_t)i * 8 * K + kb, &Bsn[ldsB + i * 512]);
        }
        __builtin_amdgcn_s_barrier();
        __builtin_amdgcn_s_setprio(1);
        #pragma unroll
        for (int mi = 0; mi < 4; mi++)
            #pragma unroll
            for (int ni = 0; ni < 4; ni++)
                acc[mi + 4][ni] = __builtin_amdgcn_mfma_f32_16x16x32_bf16(
                    bfr[ni], af[mi], acc[mi + 4][ni], 0, 0, 0);
        __builtin_amdgcn_s_setprio(0);
        __builtin_amdgcn_s_barrier();

        // ---- phase 2: read B(ks1) + A(ks1,mi0-3); MFMA ----
        #pragma unroll
        for (int ni = 0; ni < 4; ni++)
            bfr[ni] = *(const bf16x8*)&Bsb[(waveN * 64 + ni * 16 + l15) * 64 + p1];
        #pragma unroll
        for (int mi = 0; mi < 4; mi++)
            af[mi] = *(const bf16x8*)&Asb[(waveM * 128 + mi * 16 + l15) * 64 + p1];
        __builtin_amdgcn_s_barrier();
        __builtin_amdgcn_s_setprio(1);
        #pragma unroll
        for (int mi = 0; mi < 4; mi++)
            #pragma unroll
            for (int ni = 0; ni < 4; ni++)
                acc[mi][ni] = __builtin_amdgcn_mfma_f32_16x16x32_bf16(
                    bfr[ni], af[mi], acc[mi][ni], 0, 0, 0);
        __builtin_amdgcn_s_setprio(0);
        __builtin_amdgcn_s_barrier();

        // ---- phase 3: read A(ks1,mi4-7); MFMA; tile-boundary full sync ----
        #pragma unroll
        for (int mi = 0; mi < 4; mi++)
            af[mi] = *(const bf16x8*)&Asb[(waveM * 128 + (mi + 4) * 16 + l15) * 64 + p1];
        __builtin_amdgcn_s_setprio(1);
        #pragma unroll
        for (int mi = 0; mi < 4; mi++)
            #pragma unroll
            for (int ni = 0; ni < 4; ni++)
                acc[mi + 4][ni] = __builtin_amdgcn_mfma_f32_16x16x32_bf16(
                    bfr[ni], af[mi], acc[mi + 4][ni], 0, 0, 0);
        __builtin_amdgcn_s_setprio(0);
        __syncthreads();   // drains vmcnt (staging) + lgkm; gates buffer swap
    }

    #pragma unroll
    for (int mi = 0; mi < 8; mi++)
    #pragma unroll
    for (int ni = 0; ni < 4; ni++) {
        size_t row = rowBase + waveM * 128 + mi * 16 + l15;
        size_t col = colBase + waveN * 64 + ni * 16 + quad * 4;
        f32x4 v = acc[mi][ni];
        if (EPI == 1) {
            float4 b4 = *(const float4*)&bias[col];
            float4 r4 = *(const float4*)&resid[row * N + col];
            float4 o;
            o.x = v[0] + b4.x + r4.x; o.y = v[1] + b4.y + r4.y;
            o.z = v[2] + b4.z + r4.z; o.w = v[3] + b4.w + r4.w;
            *(float4*)&((float*)Cout)[row * N + col] = o;
        } else if (EPI == 2) {
            float4 b4 = *(const float4*)&bias[col];
            bf16x4 pk;
            #pragma unroll
            for (int r = 0; r < 4; r++) {
                float t2 = v[r] + ((const float*)&b4)[r];
                pk[r] = (__bf16)(0.5f * t2 * (1.0f + erff(t2 * 0.70710678118654752f)));
            }
            *(bf16x4*)&((__bf16*)Cout)[row * N + col] = pk;
        } else {
            bf16x4 pk;
            #pragma unroll
            for (int r = 0; r < 4; r++) pk[r] = (__bf16)(v[r] * sc);
            *(bf16x4*)&((__bf16*)Cout)[row * N + col] = pk;
        }
    }
}

// ---------------------------------------------------------------------------
// GEMM 256x128 tile, BK=64, 8 waves (4Mx2N), double-buffered LDS (96KB),
// same phase-overlap schedule as gemm256 (2 phases/K-tile, staging inside
// compute). For N=1024 outputs: grid (M/256)*(N/128) = 256 blocks.
// Per-wave output 64x64 (acc[4][4]).
// ---------------------------------------------------------------------------
template <int EPI>
__global__ __launch_bounds__(512, 2) void gemm256x128(const __bf16* __restrict__ A,
                                                      const __bf16* __restrict__ Bt,
                                                      const float* __restrict__ bias,
                                                      const float* __restrict__ resid,
                                                      void* __restrict__ Cout,
                                                      int M, int N, int K,
                                                      float scale) {
    __shared__ __bf16 As[2][256 * 64];   // 64 KB
    __shared__ __bf16 Bs[2][128 * 64];   // 32 KB
    int tid  = threadIdx.x;
    int lane = tid & 63, wid = tid >> 6;          // 8 waves
    int quad = lane >> 4, l15 = lane & 15;
    int waveM = wid >> 1, waveN = wid & 1;        // 4 x 2

    int GX = N >> 7;
    int id = blockIdx.x;
    int x8 = id & 7, tt = id >> 3;
    size_t rowBase = (size_t)((tt / GX) * 8 + x8) * 256;
    size_t colBase = (size_t)(tt % GX) * 128;

    int lrow8  = lane >> 3;
    int lchunk = (lane & 7) ^ lrow8;              // inverse-swizzled source
    const __bf16* Ag0 = A  + (rowBase + wid * 32 + lrow8) * (size_t)K + lchunk * 8;
    const __bf16* Bg0 = Bt + (colBase + wid * 16 + lrow8) * (size_t)K + lchunk * 8;
    int ldsA = (wid * 32) * 64;                   // wave stages 32 A-rows
    int ldsB = (wid * 16) * 64;                   // wave stages 16 B-rows

    f32x4 acc[4][4] = {};
    int swz = l15 & 7;
    int nsteps = K >> 6;

    // prologue: stage tile 0 into buf 0 (A: 4 loads, B: 2 loads per thread)
    #pragma unroll
    for (int i = 0; i < 4; i++)
        gll16(Ag0 + (size_t)i * 8 * K, &As[0][ldsA + i * 512]);
    #pragma unroll
    for (int i = 0; i < 2; i++)
        gll16(Bg0 + (size_t)i * 8 * K, &Bs[0][ldsB + i * 512]);
    __syncthreads();

    for (int t = 0; t < nsteps; t++) {
        int cur = t & 1;
        const __bf16* Asb = &As[cur][0];
        const __bf16* Bsb = &Bs[cur][0];
        __bf16* Asn = &As[cur ^ 1][0];
        __bf16* Bsn = &Bs[cur ^ 1][0];
        bool pre = (t + 1 < nsteps);
        size_t kb = (size_t)(t + 1) << 6;

        bf16x8 af[4], bfr[4];
        int p0 = (quad ^ swz) * 8;
        int p1 = ((4 + quad) ^ swz) * 8;

        // ---- phase 0: read B(ks0)+A(ks0); stage next-A; 16 MFMA ----
        #pragma unroll
        for (int ni = 0; ni < 4; ni++)
            bfr[ni] = *(const bf16x8*)&Bsb[(waveN * 64 + ni * 16 + l15) * 64 + p0];
        #pragma unroll
        for (int mi = 0; mi < 4; mi++)
            af[mi] = *(const bf16x8*)&Asb[(waveM * 64 + mi * 16 + l15) * 64 + p0];
        if (pre) {
            #pragma unroll
            for (int i = 0; i < 4; i++)
                gll16(Ag0 + (size_t)i * 8 * K + kb, &Asn[ldsA + i * 512]);
        }
        __builtin_amdgcn_s_barrier();
        __builtin_amdgcn_s_setprio(1);
        #pragma unroll
        for (int mi = 0; mi < 4; mi++)
            #pragma unroll
            for (int ni = 0; ni < 4; ni++)
                acc[mi][ni] = __builtin_amdgcn_mfma_f32_16x16x32_bf16(
                    bfr[ni], af[mi], acc[mi][ni], 0, 0, 0);
        __builtin_amdgcn_s_setprio(0);
        __builtin_amdgcn_s_barrier();

        // ---- phase 1: read B(ks1)+A(ks1); stage next-B; 16 MFMA ----
        #pragma unroll
        for (int ni = 0; ni < 4; ni++)
            bfr[ni] = *(const bf16x8*)&Bsb[(waveN * 64 + ni * 16 + l15) * 64 + p1];
        #pragma unroll
        for (int mi = 0; mi < 4; mi++)
            af[mi] = *(const bf16x8*)&Asb[(waveM * 64 + mi * 16 + l15) * 64 + p1];
        if (pre) {
            #pragma unroll
            for (int i = 0; i < 2; i++)
                gll16(Bg0 + (size_t)i * 8 * K + kb, &Bsn[ldsB + i * 512]);
        }
        __builtin_amdgcn_s_barrier();
        __builtin_amdgcn_s_setprio(1);
        #pragma unroll
        for (int mi = 0; mi < 4; mi++)
            #pragma unroll
            for (int ni = 0; ni < 4; ni++)
                acc[mi][ni] = __builtin_amdgcn_mfma_f32_16x16x32_bf16(
                    bfr[ni], af[mi], acc[mi][ni], 0, 0, 0);
        __builtin_amdgcn_s_setprio(0);
        __syncthreads();   // drains staging vmcnt + lgkm; gates buffer swap
    }

    #pragma unroll
    for (int mi = 0; mi < 4; mi++)
    #pragma unroll
    for (int ni = 0; ni < 4; ni++) {
        size_t row = rowBase + waveM * 64 + mi * 16 + l15;
        size_t col = colBase + waveN * 64 + ni * 16 + quad * 4;
        f32x4 v = acc[mi][ni];
        if (EPI == 1) {
            float4 b4 = *(const float4*)&bias[col];
            float4 r4 = *(const float4*)&resid[row * N + col];
            float4 o;
            o.x = v[0] + b4.x + r4.x; o.y = v[1] + b4.y + r4.y;
            o.z = v[2] + b4.z + r4.z; o.w = v[3] + b4.w + r4.w;
            *(float4*)&((float*)Cout)[row * N + col] = o;
        } else if (EPI == 2) {
            float4 b4 = *(const float4*)&bias[col];
            bf16x4 pk;
            #pragma unroll
            for (int r = 0; r < 4; r++) {
                float t2 = v[r] + ((const float*)&b4)[r];
                pk[r] = (__bf16)(0.5f * t2 * (1.0f + erff(t2 * 0.70710678118654752f)));
            }
            *(bf16x4*)&((__bf16*)Cout)[row * N + col] = pk;
        } else {
            bf16x4 pk;
            #pragma unroll
            for (int r = 0; r < 4; r++) pk[r] = (__bf16)(v[r] * scale);
            *(bf16x4*)&((__bf16*)Cout)[row * N + col] = pk;
        }
    }
}

// ---------------------------------------------------------------------------
// V projection GEMM (non-swapped MFMA) writing V^T [E, M], packed stores.
// ---------------------------------------------------------------------------
__global__ __launch_bounds__(256) void gemmV(const __bf16* __restrict__ A,
                                             const __bf16* __restrict__ Bt,
                                             __bf16* __restrict__ Cout,
                                             int M, int N, int K) {
    __shared__ __bf16 As[128 * 64];
    __shared__ __bf16 Bs[128 * 64];
    int tid  = threadIdx.x;
    int lane = tid & 63, wid = tid >> 6;
    int quad = lane >> 4, l15 = lane & 15;
    int waveM = wid >> 1, waveN = wid & 1;

    int GX = N >> 7;
    int id = blockIdx.x;
    int x8 = id & 7, t = id >> 3;
    size_t rowBase = (size_t)((t / GX) * 8 + x8) * 128;
    size_t colBase = (size_t)(t % GX) * 128;

    int lrow8  = lane >> 3;
    int lchunk = (lane & 7) ^ lrow8;
    const __bf16* Ag0 = A  + (rowBase + wid * 32 + lrow8) * (size_t)K + lchunk * 8;
    const __bf16* Bg0 = Bt + (colBase + wid * 32 + lrow8) * (size_t)K + lchunk * 8;
    __bf16* AsB = &As[(wid * 32) * 64];
    __bf16* BsB = &Bs[(wid * 32) * 64];

    f32x4 acc[4][4] = {};
    int swz = l15 & 7;

    for (int kb = 0; kb < K; kb += 64) {
        __syncthreads();
        #pragma unroll
        for (int i = 0; i < 4; i++) {
            gll16(Ag0 + (size_t)i * 8 * K + kb, AsB + i * 512);
            gll16(Bg0 + (size_t)i * 8 * K + kb, BsB + i * 512);
        }
        __syncthreads();
        #pragma unroll
        for (int ks = 0; ks < 2; ks++) {
            int p = ((ks * 4 + quad) ^ swz) * 8;
            bf16x8 af[4], bfr[4];
            #pragma unroll
            for (int mi = 0; mi < 4; mi++)
                af[mi] = *(const bf16x8*)&As[(waveM * 64 + mi * 16 + l15) * 64 + p];
            #pragma unroll
            for (int ni = 0; ni < 4; ni++)
                bfr[ni] = *(const bf16x8*)&Bs[(waveN * 64 + ni * 16 + l15) * 64 + p];
            #pragma unroll
            for (int mi = 0; mi < 4; mi++)
                #pragma unroll
                for (int ni = 0; ni < 4; ni++)
                    acc[mi][ni] = __builtin_amdgcn_mfma_f32_16x16x32_bf16(
                        af[mi], bfr[ni], acc[mi][ni], 0, 0, 0);
        }
    }

    #pragma unroll
    for (int mi = 0; mi < 4; mi++)
    #pragma unroll
    for (int ni = 0; ni < 4; ni++) {
        size_t col = colBase + waveN * 64 + ni * 16 + l15;        // dim in E
        size_t m0  = rowBase + waveM * 64 + mi * 16 + quad * 4;   // token
        bf16x4 pk;
        #pragma unroll
        for (int r = 0; r < 4; r++) pk[r] = (__bf16)acc[mi][ni][r];
        *(bf16x4*)&Cout[col * M + m0] = pk;
    }
}

// ---------------------------------------------------------------------------
// Flash attention, transposed-score formulation, 512 threads (8 waves).
// Each wave owns 32 q-rows (2 groups of 16). PV uses 16x16x16 MFMA.
// ---------------------------------------------------------------------------
__global__ __launch_bounds__(512, 4) void attn_kernel(const __bf16* __restrict__ QK,
                                                      const __bf16* __restrict__ Vt,
                                                      const int* __restrict__ mask,
                                                      __bf16* __restrict__ Out) {
    const int S = 2048, E = 1024, E2 = 2048, M = 8192;
    int qt = blockIdx.x, bh = blockIdx.y;
    int b = bh >> 4, h = bh & 15;
    int q0 = qt * 256;
    int tid = threadIdx.x, lane = tid & 63, wid = tid >> 6;  // wid 0..7
    int quad = lane >> 4, l15 = lane & 15;

    __shared__ __bf16 Ks[2][4096];
    __shared__ __bf16 Vs[2][4096];

    bf16x8 aq[2][2];
    #pragma unroll
    for (int g = 0; g < 2; g++)
    #pragma unroll
    for (int hh = 0; hh < 2; hh++) {
        size_t row = (size_t)(b * S + q0 + wid * 32 + g * 16 + l15);
        aq[g][hh] = *(const bf16x8*)(QK + row * E2 + h * 64 + hh * 32 + quad * 8);
    }

    int lrow8  = lane >> 3;
    int lchunk = (lane & 7) ^ lrow8;
    const __bf16* Kg0 = QK + (size_t)(b * S + wid * 8 + lrow8) * E2 + 1024 + h * 64 + lchunk * 8;

    // V reg-staging: thread (rv, cv) loads global 16B chunk cv of V^T row rv.
    int rv = tid >> 3, cv = tid & 7;
    const __bf16* Vg0 = Vt + (size_t)(h * 64 + rv) * M + b * S + cv * 8;
    int c0   = ((cv & 1) << 2) + (cv >> 2);
    int lowb = (cv >> 1) & 1;
    int sv   = rv & 7;
    int wo0  = rv * 64 + ((c0 ^ sv) << 3) + (lowb << 2);
    int wo1  = rv * 64 + (((c0 + 2) ^ sv) << 3) + (lowb << 2);

    int swz = l15 & 7;

    f32x4 accO[2][4] = {};
    f32x2 acc2[2] = {};

    bf16x8 vreg = *(const bf16x8*)(Vg0);
    gll16(Kg0, &Ks[0][wid * 512]);
    *(bf16x4*)&Vs[0][wo0] = __builtin_shufflevector(vreg, vreg, 0, 1, 2, 3);
    *(bf16x4*)&Vs[0][wo1] = __builtin_shufflevector(vreg, vreg, 4, 5, 6, 7);
    __syncthreads();

    for (int kt = 0; kt < S / 64; kt++) {
        int k0 = kt * 64;
        int buf = kt & 1;
        if (kt + 1 < S / 64) {
            vreg = *(const bf16x8*)(Vg0 + k0 + 64);            // issue early (T14)
            gll16(Kg0 + (size_t)(k0 + 64) * E2, &Ks[buf ^ 1][wid * 512]);
        }
        const __bf16* Ksb = &Ks[buf][0];
        const __bf16* Vsb = &Vs[buf][0];

        bf16x4 pb[2][4];
        #pragma unroll
        for (int nt = 0; nt < 4; nt++) {
            bf16x8 a0 = *(const bf16x8*)&Ksb[(nt * 16 + l15) * 64 + ((quad) ^ swz) * 8];
            bf16x8 a1 = *(const bf16x8*)&Ksb[(nt * 16 + l15) * 64 + ((4 + quad) ^ swz) * 8];
            int4 mz = *(const int4*)&mask[b * S + k0 + nt * 16 + quad * 4];
            #pragma unroll
            for (int g = 0; g < 2; g++) {
                f32x4 a = {};
                a = __builtin_amdgcn_mfma_f32_16x16x32_bf16(a0, aq[g][0], a, 0, 0, 0);
                a = __builtin_amdgcn_mfma_f32_16x16x32_bf16(a1, aq[g][1], a, 0, 0, 0);
                float p0 = mz.x ? EXP2(a[0]) : 0.f;
                float p1 = mz.y ? EXP2(a[1]) : 0.f;
                float p2 = mz.z ? EXP2(a[2]) : 0.f;
                float p3 = mz.w ? EXP2(a[3]) : 0.f;
                f32x2 t01; t01[0] = p0; t01[1] = p1;
                f32x2 t23; t23[0] = p2; t23[1] = p3;
                acc2[g] += t01 + t23;
                bf16x4 pk;
                pk[0] = (__bf16)p0; pk[1] = (__bf16)p1;
                pk[2] = (__bf16)p2; pk[3] = (__bf16)p3;
                pb[g][nt] = pk;
            }
        }

        // PV: 2x b128 per dt; halves are nt fragments, shared by both groups.
        #pragma unroll
        for (int dt = 0; dt < 4; dt++) {
            const __bf16* vrow = &Vsb[(dt * 16 + l15) * 64];
            bf16x8 vv0 = *(const bf16x8*)&vrow[((quad * 2 + 0) ^ swz) * 8];
            bf16x8 vv1 = *(const bf16x8*)&vrow[((quad * 2 + 1) ^ swz) * 8];
            bf16x4 h00 = __builtin_shufflevector(vv0, vv0, 0, 1, 2, 3);
            bf16x4 h01 = __builtin_shufflevector(vv0, vv0, 4, 5, 6, 7);
            bf16x4 h10 = __builtin_shufflevector(vv1, vv1, 0, 1, 2, 3);
            bf16x4 h11 = __builtin_shufflevector(vv1, vv1, 4, 5, 6, 7);
            #pragma unroll
            for (int g = 0; g < 2; g++) {
                accO[g][dt] = mfma16x16(h00, pb[g][0], accO[g][dt]);
                accO[g][dt] = mfma16x16(h01, pb[g][1], accO[g][dt]);
                accO[g][dt] = mfma16x16(h10, pb[g][2], accO[g][dt]);
                accO[g][dt] = mfma16x16(h11, pb[g][3], accO[g][dt]);
            }
        }

        if (kt + 1 < S / 64) {
            // write-late half of the async stage (vmcnt wait lands here)
            *(bf16x4*)&Vs[buf ^ 1][wo0] = __builtin_shufflevector(vreg, vreg, 0, 1, 2, 3);
            *(bf16x4*)&Vs[buf ^ 1][wo1] = __builtin_shufflevector(vreg, vreg, 4, 5, 6, 7);
        }
        __syncthreads();
    }

    #pragma unroll
    for (int g = 0; g < 2; g++) {
        float l = acc2[g][0] + acc2[g][1];
        l += __shfl_xor(l, 16, 64);
        l += __shfl_xor(l, 32, 64);
        float inv = 1.0f / l;
        #pragma unroll
        for (int dt = 0; dt < 4; dt++) {
            size_t row = (size_t)(b * S + q0 + wid * 32 + g * 16 + l15);
            bf16x4 pk;
            #pragma unroll
            for (int r = 0; r < 4; r++) pk[r] = (__bf16)(accO[g][dt][r] * inv);
            *(bf16x4*)&Out[row * E + h * 64 + dt * 16 + quad * 4] = pk;
        }
    }
}

// ---------------------------------------------------------------------------
// Launch
// ---------------------------------------------------------------------------
extern "C" void kernel_launch(void* const* d_in, const int* in_sizes, int n_in,
                              void* d_out, int out_size, void* d_ws, size_t ws_size,
                              hipStream_t stream) {
    const int Bb = 4, S = 2048, E = 1024, FF = 4096;
    const int M = Bb * S;  // 8192

    const float* value = (const float*)d_in[0];
    const float* key   = (const float*)d_in[1];
    const float* query = (const float*)d_in[2];
    const int*   mask  = (const int*)d_in[3];
    const float* Wv    = (const float*)d_in[4];
    const float* Wk    = (const float*)d_in[5];
    const float* Wq    = (const float*)d_in[6];
    const float* Wo    = (const float*)d_in[7];
    const float* bo    = (const float*)d_in[8];
    const float* ln1_g = (const float*)d_in[9];
    const float* ln1_b = (const float*)d_in[10];
    const float* ln2_g = (const float*)d_in[11];
    const float* ln2_b = (const float*)d_in[12];
    const float* lnf_g = (const float*)d_in[13];
    const float* lnf_b = (const float*)d_in[14];
    const float* W1    = (const float*)d_in[15];
    const float* b1    = (const float*)d_in[16];
    const float* W2    = (const float*)d_in[17];
    const float* b2    = (const float*)d_in[18];

    char* ws = (char*)d_ws;
    const size_t MB = 1024 * 1024;
    __bf16* Wqt = (__bf16*)(ws + 0 * MB);
    __bf16* Wkt = (__bf16*)(ws + 2 * MB);
    __bf16* Wvt = (__bf16*)(ws + 4 * MB);
    __bf16* Wot = (__bf16*)(ws + 6 * MB);
    __bf16* W1t = (__bf16*)(ws + 8 * MB);    // [FF, E]
    __bf16* W2t = (__bf16*)(ws + 16 * MB);   // [E, FF]
    __bf16* q_bf = (__bf16*)(ws + 24 * MB);
    __bf16* k_bf = (__bf16*)(ws + 40 * MB);
    __bf16* v_bf = (__bf16*)(ws + 56 * MB);
    __bf16* QKb  = (__bf16*)(ws + 72 * MB);  // [M, 2E]
    __bf16* Vtg  = (__bf16*)(ws + 104 * MB); // V^T [E, M]
    __bf16* attn = q_bf;
    __bf16* x_ln = k_bf;
    __bf16* h1   = v_bf;                     // [M, FF] 64MB
    float*  qln  = (float*)(ws + 120 * MB);
    float*  x32  = (float*)(ws + 152 * MB);

    transpose_all<<<12288, 256, 0, stream>>>(Wq, Wk, Wv, Wo, W1, W2,
                                             Wqt, Wkt, Wvt, Wot, W1t, W2t);

    ln3_kernel<<<dim3(M, 3), 256, 0, stream>>>(query, key, value,
                                               ln1_g, ln1_b, ln2_g, ln2_b,
                                               qln, q_bf, k_bf, v_bf);

    // merged Q|K projection -> QKb [M, 2E]; Q side scaled (1/8)*log2(e).
    // 256² 4-phase: grid (8192/256)*(2048/256) = 32*8 = 256.
    gemm256<0><<<256, 512, 0, stream>>>(
        q_bf, k_bf, Wqt, Wkt, nullptr, nullptr, QKb, M, 2 * E, E, E,
        0.125f * 1.44269504088896f);

    // V projection -> V^T [E, M]. grid 8*64 (128² kept: transposed epilogue).
    gemmV<<<8 * 64, 256, 0, stream>>>(v_bf, Wvt, Vtg, M, E, E);

    attn_kernel<<<dim3(S / 256, Bb * 16), 512, 0, stream>>>(QKb, Vtg, mask, attn);

    // out proj + bias + residual(qln) -> x32 (f32). 256x128 phase-overlap.
    gemm256x128<1><<<256, 512, 0, stream>>>(
        attn, Wot, bo, qln, x32, M, E, E, 1.0f);

    ln_kernel<<<M, 256, 0, stream>>>(x32, lnf_g, lnf_b, x_ln);

    // FFN1: 256² 4-phase: grid (8192/256)*(4096/256) = 32*16 = 512.
    gemm256<2><<<512, 512, 0, stream>>>(
        x_ln, x_ln, W1t, W1t, b1, nullptr, h1, M, FF, E, FF, 1.0f);
    // FFN2: 256x128 phase-overlap, K=4096. grid 256.
    gemm256x128<1><<<256, 512, 0, stream>>>(
        h1, W2t, b2, x32, (float*)d_out, M, E, FF, 1.0f);
}